// Round 1
// baseline (316.432 us; speedup 1.0000x reference)
//
#include <hip/hip_runtime.h>

// MHA: B=2 S=2048 D=1024 H=16 DH=64.  All GEMMs bf16 MFMA 16x16x32, fp32 acc.
// ws layout: q[8MB | b,h,s,dh] k[8MB | b,h,s,dh] v[8MB | b,h,dh,s (transposed)] o[8MB | b,s,d]

typedef __bf16 bf16;
typedef bf16 bf16x8 __attribute__((ext_vector_type(8)));
typedef float f32x4 __attribute__((ext_vector_type(4)));

#define MFMA_BF16(a, b, c) __builtin_amdgcn_mfma_f32_16x16x32_bf16(a, b, c, 0, 0, 0)

// ---------------------------------------------------------------------------
// Kernel 1: fused QKV projection.  C[m,n] = sum_k x[m,k] * W[n,k] + bias[n]
// grid (32 Mtiles, 8 Ntiles, 3 matrices), 256 threads.
// ---------------------------------------------------------------------------
__global__ __launch_bounds__(256)
void qkv_gemm(const float* __restrict__ x,
              const float* __restrict__ Wq, const float* __restrict__ bq,
              const float* __restrict__ Wk, const float* __restrict__ bk,
              const float* __restrict__ Wv, const float* __restrict__ bv,
              bf16* __restrict__ q_ws, bf16* __restrict__ k_ws, bf16* __restrict__ v_ws)
{
    const int z = blockIdx.z;
    const float* W    = (z == 0) ? Wq : (z == 1) ? Wk : Wv;
    const float* bias = (z == 0) ? bq : (z == 1) ? bk : bv;

    __shared__ bf16 As[128][32];
    __shared__ bf16 Bs[128][32];

    const int m0 = blockIdx.x * 128;
    const int n0 = blockIdx.y * 128;
    const int t    = threadIdx.x;
    const int wave = t >> 6;
    const int lane = t & 63;
    const int lr   = lane & 15;
    const int quad = lane >> 4;
    const int wm = (wave & 1) * 64;
    const int wn = (wave >> 1) * 64;

    const int srow = t >> 1;          // 0..127 staging row
    const int scol = (t & 1) * 16;    // 0 or 16

    f32x4 acc[4][4] = {};

    for (int k0 = 0; k0 < 1024; k0 += 32) {
        const float* asrc = x + (size_t)(m0 + srow) * 1024 + k0 + scol;
        const float* bsrc = W + (size_t)(n0 + srow) * 1024 + k0 + scol;
        float4 a0 = ((const float4*)asrc)[0];
        float4 a1 = ((const float4*)asrc)[1];
        float4 a2 = ((const float4*)asrc)[2];
        float4 a3 = ((const float4*)asrc)[3];
        float4 b0 = ((const float4*)bsrc)[0];
        float4 b1 = ((const float4*)bsrc)[1];
        float4 b2 = ((const float4*)bsrc)[2];
        float4 b3 = ((const float4*)bsrc)[3];
        bf16x8 pa0 = {(bf16)a0.x,(bf16)a0.y,(bf16)a0.z,(bf16)a0.w,(bf16)a1.x,(bf16)a1.y,(bf16)a1.z,(bf16)a1.w};
        bf16x8 pa1 = {(bf16)a2.x,(bf16)a2.y,(bf16)a2.z,(bf16)a2.w,(bf16)a3.x,(bf16)a3.y,(bf16)a3.z,(bf16)a3.w};
        bf16x8 pb0 = {(bf16)b0.x,(bf16)b0.y,(bf16)b0.z,(bf16)b0.w,(bf16)b1.x,(bf16)b1.y,(bf16)b1.z,(bf16)b1.w};
        bf16x8 pb1 = {(bf16)b2.x,(bf16)b2.y,(bf16)b2.z,(bf16)b2.w,(bf16)b3.x,(bf16)b3.y,(bf16)b3.z,(bf16)b3.w};
        *(bf16x8*)&As[srow][scol]     = pa0;
        *(bf16x8*)&As[srow][scol + 8] = pa1;
        *(bf16x8*)&Bs[srow][scol]     = pb0;
        *(bf16x8*)&Bs[srow][scol + 8] = pb1;
        __syncthreads();

        bf16x8 af[4], bfr[4];
        #pragma unroll
        for (int i = 0; i < 4; i++) af[i]  = *(const bf16x8*)&As[wm + i*16 + lr][quad*8];
        #pragma unroll
        for (int j = 0; j < 4; j++) bfr[j] = *(const bf16x8*)&Bs[wn + j*16 + lr][quad*8];
        #pragma unroll
        for (int i = 0; i < 4; i++)
            #pragma unroll
            for (int j = 0; j < 4; j++)
                acc[i][j] = MFMA_BF16(af[i], bfr[j], acc[i][j]);
        __syncthreads();
    }

    // epilogue: add bias, scatter into head-major q/k and transposed v
    #pragma unroll
    for (int j = 0; j < 4; j++) {
        const int col = n0 + wn + j * 16 + lr;   // 0..1023 output feature
        const float bb = bias[col];
        const int h  = col >> 6;
        const int dh = col & 63;
        #pragma unroll
        for (int i = 0; i < 4; i++) {
            #pragma unroll
            for (int r = 0; r < 4; r++) {
                const int row = m0 + wm + i * 16 + quad * 4 + r;  // b*2048+s
                const int bi = row >> 11;
                const int si = row & 2047;
                const float val = acc[i][j][r] + bb;
                if (z == 0)
                    q_ws[(((size_t)bi * 16 + h) * 2048 + si) * 64 + dh] = (bf16)val;
                else if (z == 1)
                    k_ws[(((size_t)bi * 16 + h) * 2048 + si) * 64 + dh] = (bf16)val;
                else
                    v_ws[(((size_t)bi * 16 + h) * 64 + dh) * 2048 + si] = (bf16)val;
            }
        }
    }
}

// ---------------------------------------------------------------------------
// Kernel 2: flash attention.  grid (16 q-tiles, 32 b*h), 256 threads.
// Block handles 128 Q rows of one head; wave owns 32 rows (full softmax rows).
// ---------------------------------------------------------------------------
__global__ __launch_bounds__(256)
void attn(const bf16* __restrict__ q_ws, const bf16* __restrict__ k_ws,
          const bf16* __restrict__ v_ws, bf16* __restrict__ o_ws)
{
    const int qt = blockIdx.x;
    const int bh = blockIdx.y;           // b*16+h
    const int b_ = bh >> 4, h = bh & 15;

    const bf16* qbase = q_ws + (size_t)bh * 2048 * 64;
    const bf16* kbase = k_ws + (size_t)bh * 2048 * 64;
    const bf16* vbase = v_ws + (size_t)bh * 64 * 2048;  // [64][2048] transposed

    __shared__ bf16 Ks[128][64];     // [key][feat]
    __shared__ bf16 Vs[64][128];     // [feat][key]  (V^T tile)
    __shared__ bf16 Ps[4][32][128];  // per-wave P round-trip C-layout -> A-layout

    const int t    = threadIdx.x;
    const int wave = t >> 6;
    const int lane = t & 63;
    const int lr   = lane & 15;
    const int quad = lane >> 4;

    // Q fragments live in registers for the whole block (rows wave*32..+32)
    bf16x8 aq[2][2];
    #pragma unroll
    for (int i = 0; i < 2; i++)
        #pragma unroll
        for (int kc = 0; kc < 2; kc++)
            aq[i][kc] = *(const bf16x8*)(qbase +
                (size_t)(qt*128 + wave*32 + i*16 + lr) * 64 + kc*32 + quad*8);

    float m_i[2][4], l_i[2][4];
    #pragma unroll
    for (int i = 0; i < 2; i++)
        #pragma unroll
        for (int r = 0; r < 4; r++) { m_i[i][r] = -1e30f; l_i[i][r] = 0.f; }
    f32x4 o_acc[2][4] = {};

    const float scale = 0.125f;  // 1/sqrt(64)

    for (int kt = 0; kt < 16; kt++) {
        __syncthreads();   // previous tile's Ks/Vs reads done
        // stage K tile (contiguous copy) and V^T tile
        {
            const bf16x8* ksrc = (const bf16x8*)(kbase + (size_t)kt * 128 * 64);
            bf16x8* kdst = (bf16x8*)&Ks[0][0];
            #pragma unroll
            for (int u = 0; u < 4; u++) {
                const int c = t + u * 256;          // 0..1023
                kdst[c] = ksrc[c];
                const int d = c >> 4, off = (c & 15) * 8;
                *(bf16x8*)&Vs[d][off] =
                    *(const bf16x8*)(vbase + (size_t)d * 2048 + kt*128 + off);
            }
        }
        __syncthreads();

        // S = Q K^T  (per wave: 32 rows x 128 cols)
        f32x4 sacc[2][8];
        #pragma unroll
        for (int j = 0; j < 8; j++) {
            bf16x8 bk0 = *(const bf16x8*)&Ks[j*16 + lr][quad*8];
            bf16x8 bk1 = *(const bf16x8*)&Ks[j*16 + lr][32 + quad*8];
            #pragma unroll
            for (int i = 0; i < 2; i++) {
                f32x4 a0 = {0.f, 0.f, 0.f, 0.f};
                a0 = MFMA_BF16(aq[i][0], bk0, a0);
                a0 = MFMA_BF16(aq[i][1], bk1, a0);
                sacc[i][j] = a0;
            }
        }

        // online softmax per row (row = i*16 + quad*4 + r, cols across lr+j)
        #pragma unroll
        for (int i = 0; i < 2; i++) {
            float mx[4];
            #pragma unroll
            for (int r = 0; r < 4; r++) {
                float m = -1e30f;
                #pragma unroll
                for (int j = 0; j < 8; j++) m = fmaxf(m, sacc[i][j][r]);
                m *= scale;
                m = fmaxf(m, __shfl_xor(m, 1));
                m = fmaxf(m, __shfl_xor(m, 2));
                m = fmaxf(m, __shfl_xor(m, 4));
                m = fmaxf(m, __shfl_xor(m, 8));
                mx[r] = m;
            }
            float al[4], nm[4];
            #pragma unroll
            for (int r = 0; r < 4; r++) {
                nm[r] = fmaxf(m_i[i][r], mx[r]);
                al[r] = __expf(m_i[i][r] - nm[r]);
                m_i[i][r] = nm[r];
            }
            float rs[4] = {0.f, 0.f, 0.f, 0.f};
            #pragma unroll
            for (int j = 0; j < 8; j++)
                #pragma unroll
                for (int r = 0; r < 4; r++) {
                    float p = __expf(sacc[i][j][r] * scale - nm[r]);
                    rs[r] += p;
                    Ps[wave][i*16 + quad*4 + r][j*16 + lr] = (bf16)p;
                }
            #pragma unroll
            for (int r = 0; r < 4; r++) {
                float s = rs[r];
                s += __shfl_xor(s, 1);
                s += __shfl_xor(s, 2);
                s += __shfl_xor(s, 4);
                s += __shfl_xor(s, 8);
                l_i[i][r] = l_i[i][r] * al[r] + s;
            }
            #pragma unroll
            for (int n = 0; n < 4; n++)
                #pragma unroll
                for (int r = 0; r < 4; r++)
                    o_acc[i][n][r] *= al[r];
        }

        __syncthreads();   // P (cross-lane LDS round-trip) visible

        // O += P V   (A = P [32 x 128], B = V [128 x 64] via Vs = V^T)
        #pragma unroll
        for (int kc = 0; kc < 4; kc++) {
            bf16x8 ap0 = *(const bf16x8*)&Ps[wave][lr][kc*32 + quad*8];
            bf16x8 ap1 = *(const bf16x8*)&Ps[wave][16 + lr][kc*32 + quad*8];
            #pragma unroll
            for (int n = 0; n < 4; n++) {
                bf16x8 bv8 = *(const bf16x8*)&Vs[n*16 + lr][kc*32 + quad*8];
                o_acc[0][n] = MFMA_BF16(ap0, bv8, o_acc[0][n]);
                o_acc[1][n] = MFMA_BF16(ap1, bv8, o_acc[1][n]);
            }
        }
    }

    // epilogue: o / l, write bf16 [b,s,d]
    #pragma unroll
    for (int i = 0; i < 2; i++)
        #pragma unroll
        for (int n = 0; n < 4; n++)
            #pragma unroll
            for (int r = 0; r < 4; r++) {
                const float v = o_acc[i][n][r] / l_i[i][r];
                const int s   = qt*128 + wave*32 + i*16 + quad*4 + r;
                const int col = h*64 + n*16 + lr;
                o_ws[((size_t)b_ * 2048 + s) * 1024 + col] = (bf16)v;
            }
}

// ---------------------------------------------------------------------------
// Kernel 3: output projection.  out[m,n] = sum_k o[m,k]*Wo[n,k] + bo[n], fp32 out
// ---------------------------------------------------------------------------
__global__ __launch_bounds__(256)
void out_gemm(const bf16* __restrict__ o_ws,
              const float* __restrict__ Wo, const float* __restrict__ bo,
              float* __restrict__ out)
{
    __shared__ bf16 As[128][32];
    __shared__ bf16 Bs[128][32];

    const int m0 = blockIdx.x * 128;
    const int n0 = blockIdx.y * 128;
    const int t    = threadIdx.x;
    const int wave = t >> 6;
    const int lane = t & 63;
    const int lr   = lane & 15;
    const int quad = lane >> 4;
    const int wm = (wave & 1) * 64;
    const int wn = (wave >> 1) * 64;
    const int srow = t >> 1;
    const int scol = (t & 1) * 16;

    f32x4 acc[4][4] = {};

    for (int k0 = 0; k0 < 1024; k0 += 32) {
        const bf16*  asrc = o_ws + (size_t)(m0 + srow) * 1024 + k0 + scol;
        const float* bsrc = Wo   + (size_t)(n0 + srow) * 1024 + k0 + scol;
        *(bf16x8*)&As[srow][scol]     = ((const bf16x8*)asrc)[0];
        *(bf16x8*)&As[srow][scol + 8] = ((const bf16x8*)asrc)[1];
        float4 b0 = ((const float4*)bsrc)[0];
        float4 b1 = ((const float4*)bsrc)[1];
        float4 b2 = ((const float4*)bsrc)[2];
        float4 b3 = ((const float4*)bsrc)[3];
        bf16x8 pb0 = {(bf16)b0.x,(bf16)b0.y,(bf16)b0.z,(bf16)b0.w,(bf16)b1.x,(bf16)b1.y,(bf16)b1.z,(bf16)b1.w};
        bf16x8 pb1 = {(bf16)b2.x,(bf16)b2.y,(bf16)b2.z,(bf16)b2.w,(bf16)b3.x,(bf16)b3.y,(bf16)b3.z,(bf16)b3.w};
        *(bf16x8*)&Bs[srow][scol]     = pb0;
        *(bf16x8*)&Bs[srow][scol + 8] = pb1;
        __syncthreads();

        bf16x8 af[4], bfr[4];
        #pragma unroll
        for (int i = 0; i < 4; i++) af[i]  = *(const bf16x8*)&As[wm + i*16 + lr][quad*8];
        #pragma unroll
        for (int j = 0; j < 4; j++) bfr[j] = *(const bf16x8*)&Bs[wn + j*16 + lr][quad*8];
        #pragma unroll
        for (int i = 0; i < 4; i++)
            #pragma unroll
            for (int j = 0; j < 4; j++)
                acc[i][j] = MFMA_BF16(af[i], bfr[j], acc[i][j]);
        __syncthreads();
    }

    #pragma unroll
    for (int j = 0; j < 4; j++) {
        const int col = n0 + wn + j * 16 + lr;
        const float bb = bo[col];
        #pragma unroll
        for (int i = 0; i < 4; i++) {
            #pragma unroll
            for (int r = 0; r < 4; r++) {
                const int row = m0 + wm + i * 16 + quad * 4 + r;
                out[(size_t)row * 1024 + col] = acc[i][j][r] + bb;
            }
        }
    }
}

extern "C" void kernel_launch(void* const* d_in, const int* in_sizes, int n_in,
                              void* d_out, int out_size, void* d_ws, size_t ws_size,
                              hipStream_t stream) {
    (void)in_sizes; (void)n_in; (void)out_size; (void)ws_size;
    const float* x  = (const float*)d_in[0];
    const float* Wq = (const float*)d_in[1];
    const float* bq = (const float*)d_in[2];
    const float* Wk = (const float*)d_in[3];
    const float* bk = (const float*)d_in[4];
    const float* Wv = (const float*)d_in[5];
    const float* bv = (const float*)d_in[6];
    const float* Wo = (const float*)d_in[7];
    const float* bo = (const float*)d_in[8];
    float* out = (float*)d_out;

    char* ws = (char*)d_ws;
    bf16* q_ws = (bf16*)(ws);
    bf16* k_ws = (bf16*)(ws + (size_t)8  * 1024 * 1024);
    bf16* v_ws = (bf16*)(ws + (size_t)16 * 1024 * 1024);
    bf16* o_ws = (bf16*)(ws + (size_t)24 * 1024 * 1024);

    hipLaunchKernelGGL(qkv_gemm, dim3(32, 8, 3), dim3(256), 0, stream,
                       x, Wq, bq, Wk, bk, Wv, bv, q_ws, k_ws, v_ws);
    hipLaunchKernelGGL(attn, dim3(16, 32), dim3(256), 0, stream,
                       q_ws, k_ws, v_ws, o_ws);
    hipLaunchKernelGGL(out_gemm, dim3(32, 8), dim3(256), 0, stream,
                       o_ws, Wo, bo, out);
}

// Round 2
// 293.892 us; speedup vs baseline: 1.0767x; 1.0767x over previous
//
#include <hip/hip_runtime.h>

// MHA: B=2 S=2048 D=1024 H=16 DH=64.  All GEMMs bf16 MFMA 16x16x32, fp32 acc.
// ws layout: q[8MB | b,h,s,dh, pre-scaled by 0.125] k[8MB | b,h,s,dh]
//            v[8MB | b,h,dh,s (transposed)] o[8MB | b,s,d]
// R1: LDS bank-conflict padding everywhere (stride % 128B == 16B -> 2-way max),
//     P-buffer split into two 64-key halves (attn LDS 64KB -> 53KB, 3 blk/CU),
//     removed per-tile 3rd barrier (Ps is wave-private), Q pre-scaled (exact).

typedef __bf16 bf16;
typedef bf16 bf16x8 __attribute__((ext_vector_type(8)));
typedef float f32x4 __attribute__((ext_vector_type(4)));

#define MFMA_BF16(a, b, c) __builtin_amdgcn_mfma_f32_16x16x32_bf16(a, b, c, 0, 0, 0)

// ---------------------------------------------------------------------------
// Kernel 1: fused QKV projection.  C[m,n] = sum_k x[m,k] * W[n,k] + bias[n]
// grid (32 Mtiles, 8 Ntiles, 3 matrices), 256 threads.
// ---------------------------------------------------------------------------
__global__ __launch_bounds__(256)
void qkv_gemm(const float* __restrict__ x,
              const float* __restrict__ Wq, const float* __restrict__ bq,
              const float* __restrict__ Wk, const float* __restrict__ bk,
              const float* __restrict__ Wv, const float* __restrict__ bv,
              bf16* __restrict__ q_ws, bf16* __restrict__ k_ws, bf16* __restrict__ v_ws)
{
    const int z = blockIdx.z;
    const float* W    = (z == 0) ? Wq : (z == 1) ? Wk : Wv;
    const float* bias = (z == 0) ? bq : (z == 1) ? bk : bv;

    // stride 40 bf16 = 80 B = 20 dwords -> lanes lr spread over 8 bank groups (2-way, free)
    __shared__ bf16 As[128][40];
    __shared__ bf16 Bs[128][40];

    const int m0 = blockIdx.x * 128;
    const int n0 = blockIdx.y * 128;
    const int t    = threadIdx.x;
    const int wave = t >> 6;
    const int lane = t & 63;
    const int lr   = lane & 15;
    const int quad = lane >> 4;
    const int wm = (wave & 1) * 64;
    const int wn = (wave >> 1) * 64;

    const int srow = t >> 1;          // 0..127 staging row
    const int scol = (t & 1) * 16;    // 0 or 16

    f32x4 acc[4][4] = {};

    for (int k0 = 0; k0 < 1024; k0 += 32) {
        const float* asrc = x + (size_t)(m0 + srow) * 1024 + k0 + scol;
        const float* bsrc = W + (size_t)(n0 + srow) * 1024 + k0 + scol;
        float4 a0 = ((const float4*)asrc)[0];
        float4 a1 = ((const float4*)asrc)[1];
        float4 a2 = ((const float4*)asrc)[2];
        float4 a3 = ((const float4*)asrc)[3];
        float4 b0 = ((const float4*)bsrc)[0];
        float4 b1 = ((const float4*)bsrc)[1];
        float4 b2 = ((const float4*)bsrc)[2];
        float4 b3 = ((const float4*)bsrc)[3];
        bf16x8 pa0 = {(bf16)a0.x,(bf16)a0.y,(bf16)a0.z,(bf16)a0.w,(bf16)a1.x,(bf16)a1.y,(bf16)a1.z,(bf16)a1.w};
        bf16x8 pa1 = {(bf16)a2.x,(bf16)a2.y,(bf16)a2.z,(bf16)a2.w,(bf16)a3.x,(bf16)a3.y,(bf16)a3.z,(bf16)a3.w};
        bf16x8 pb0 = {(bf16)b0.x,(bf16)b0.y,(bf16)b0.z,(bf16)b0.w,(bf16)b1.x,(bf16)b1.y,(bf16)b1.z,(bf16)b1.w};
        bf16x8 pb1 = {(bf16)b2.x,(bf16)b2.y,(bf16)b2.z,(bf16)b2.w,(bf16)b3.x,(bf16)b3.y,(bf16)b3.z,(bf16)b3.w};
        *(bf16x8*)&As[srow][scol]     = pa0;
        *(bf16x8*)&As[srow][scol + 8] = pa1;
        *(bf16x8*)&Bs[srow][scol]     = pb0;
        *(bf16x8*)&Bs[srow][scol + 8] = pb1;
        __syncthreads();

        bf16x8 af[4], bfr[4];
        #pragma unroll
        for (int i = 0; i < 4; i++) af[i]  = *(const bf16x8*)&As[wm + i*16 + lr][quad*8];
        #pragma unroll
        for (int j = 0; j < 4; j++) bfr[j] = *(const bf16x8*)&Bs[wn + j*16 + lr][quad*8];
        #pragma unroll
        for (int i = 0; i < 4; i++)
            #pragma unroll
            for (int j = 0; j < 4; j++)
                acc[i][j] = MFMA_BF16(af[i], bfr[j], acc[i][j]);
        __syncthreads();
    }

    // epilogue: add bias, scatter into head-major q/k and transposed v.
    // Q gets pre-scaled by 1/sqrt(DH)=0.125 (exact power of 2 in bf16).
    #pragma unroll
    for (int j = 0; j < 4; j++) {
        const int col = n0 + wn + j * 16 + lr;   // 0..1023 output feature
        const float bb = bias[col];
        const int h  = col >> 6;
        const int dh = col & 63;
        #pragma unroll
        for (int i = 0; i < 4; i++) {
            #pragma unroll
            for (int r = 0; r < 4; r++) {
                const int row = m0 + wm + i * 16 + quad * 4 + r;  // b*2048+s
                const int bi = row >> 11;
                const int si = row & 2047;
                const float val = acc[i][j][r] + bb;
                if (z == 0)
                    q_ws[(((size_t)bi * 16 + h) * 2048 + si) * 64 + dh] = (bf16)(val * 0.125f);
                else if (z == 1)
                    k_ws[(((size_t)bi * 16 + h) * 2048 + si) * 64 + dh] = (bf16)val;
                else
                    v_ws[(((size_t)bi * 16 + h) * 64 + dh) * 2048 + si] = (bf16)val;
            }
        }
    }
}

// ---------------------------------------------------------------------------
// Kernel 2: flash attention.  grid (16 q-tiles, 32 b*h), 256 threads.
// Block handles 128 Q rows of one head; wave owns 32 rows (full softmax rows).
// LDS: Ks 18KB + Vs 17KB + Ps 18KB = 53KB -> 3 blocks/CU.
// ---------------------------------------------------------------------------
__global__ __launch_bounds__(256)
void attn(const bf16* __restrict__ q_ws, const bf16* __restrict__ k_ws,
          const bf16* __restrict__ v_ws, bf16* __restrict__ o_ws)
{
    const int qt = blockIdx.x;
    const int bh = blockIdx.y;           // b*16+h
    const int b_ = bh >> 4, h = bh & 15;

    const bf16* qbase = q_ws + (size_t)bh * 2048 * 64;
    const bf16* kbase = k_ws + (size_t)bh * 2048 * 64;
    const bf16* vbase = v_ws + (size_t)bh * 64 * 2048;  // [64][2048] transposed

    // padded strides: 72 = 144B = 36 dw (adv 4/row), 136 = 272B = 68 dw (adv 4/row)
    __shared__ bf16 Ks[128][72];     // [key][feat]
    __shared__ bf16 Vs[64][136];     // [feat][key]  (V^T tile)
    __shared__ bf16 Ps[4][32][72];   // per-wave P half-tile (64 keys at a time)

    const int t    = threadIdx.x;
    const int wave = t >> 6;
    const int lane = t & 63;
    const int lr   = lane & 15;
    const int quad = lane >> 4;

    // Q fragments (pre-scaled) live in registers for the whole block
    bf16x8 aq[2][2];
    #pragma unroll
    for (int i = 0; i < 2; i++)
        #pragma unroll
        for (int kc = 0; kc < 2; kc++)
            aq[i][kc] = *(const bf16x8*)(qbase +
                (size_t)(qt*128 + wave*32 + i*16 + lr) * 64 + kc*32 + quad*8);

    float m_i[2][4], l_i[2][4];
    #pragma unroll
    for (int i = 0; i < 2; i++)
        #pragma unroll
        for (int r = 0; r < 4; r++) { m_i[i][r] = -1e30f; l_i[i][r] = 0.f; }
    f32x4 o_acc[2][4] = {};

    for (int kt = 0; kt < 16; kt++) {
        __syncthreads();   // previous tile's Ks/Vs reads done
        // stage K tile and V^T tile (padded rows)
        {
            const bf16x8* ksrc = (const bf16x8*)(kbase + (size_t)kt * 128 * 64);
            #pragma unroll
            for (int u = 0; u < 4; u++) {
                const int c = t + u * 256;          // 0..1023
                *(bf16x8*)&Ks[c >> 3][(c & 7) * 8] = ksrc[c];
                const int d = c >> 4, off = (c & 15) * 8;
                *(bf16x8*)&Vs[d][off] =
                    *(const bf16x8*)(vbase + (size_t)d * 2048 + kt*128 + off);
            }
        }
        __syncthreads();

        // S = Q K^T  (per wave: 32 rows x 128 cols); Q pre-scaled so S is scaled
        f32x4 sacc[2][8];
        #pragma unroll
        for (int j = 0; j < 8; j++) {
            bf16x8 bk0 = *(const bf16x8*)&Ks[j*16 + lr][quad*8];
            bf16x8 bk1 = *(const bf16x8*)&Ks[j*16 + lr][32 + quad*8];
            #pragma unroll
            for (int i = 0; i < 2; i++) {
                f32x4 a0 = {0.f, 0.f, 0.f, 0.f};
                a0 = MFMA_BF16(aq[i][0], bk0, a0);
                a0 = MFMA_BF16(aq[i][1], bk1, a0);
                sacc[i][j] = a0;
            }
        }

        // online softmax per row; p overwrites sacc in-place
        #pragma unroll
        for (int i = 0; i < 2; i++) {
            float nm[4], al[4];
            #pragma unroll
            for (int r = 0; r < 4; r++) {
                float m = -1e30f;
                #pragma unroll
                for (int j = 0; j < 8; j++) m = fmaxf(m, sacc[i][j][r]);
                m = fmaxf(m, __shfl_xor(m, 1));
                m = fmaxf(m, __shfl_xor(m, 2));
                m = fmaxf(m, __shfl_xor(m, 4));
                m = fmaxf(m, __shfl_xor(m, 8));
                nm[r] = fmaxf(m_i[i][r], m);
                al[r] = __expf(m_i[i][r] - nm[r]);
                m_i[i][r] = nm[r];
            }
            float rs[4] = {0.f, 0.f, 0.f, 0.f};
            #pragma unroll
            for (int j = 0; j < 8; j++)
                #pragma unroll
                for (int r = 0; r < 4; r++) {
                    float p = __expf(sacc[i][j][r] - nm[r]);
                    sacc[i][j][r] = p;
                    rs[r] += p;
                }
            #pragma unroll
            for (int r = 0; r < 4; r++) {
                float s = rs[r];
                s += __shfl_xor(s, 1);
                s += __shfl_xor(s, 2);
                s += __shfl_xor(s, 4);
                s += __shfl_xor(s, 8);
                l_i[i][r] = l_i[i][r] * al[r] + s;
            }
            #pragma unroll
            for (int n = 0; n < 4; n++)
                #pragma unroll
                for (int r = 0; r < 4; r++)
                    o_acc[i][n][r] *= al[r];
        }

        // O += P V in two 64-key halves through the wave-private Ps buffer.
        // No barrier needed: Ps is per-wave, compiler orders via lgkmcnt.
        #pragma unroll
        for (int half = 0; half < 2; half++) {
            #pragma unroll
            for (int i = 0; i < 2; i++)
                #pragma unroll
                for (int j = 0; j < 4; j++)
                    #pragma unroll
                    for (int r = 0; r < 4; r++)
                        Ps[wave][i*16 + quad*4 + r][j*16 + lr] =
                            (bf16)sacc[i][half*4 + j][r];
            #pragma unroll
            for (int kc = 0; kc < 2; kc++) {
                bf16x8 ap0 = *(const bf16x8*)&Ps[wave][lr][kc*32 + quad*8];
                bf16x8 ap1 = *(const bf16x8*)&Ps[wave][16 + lr][kc*32 + quad*8];
                #pragma unroll
                for (int n = 0; n < 4; n++) {
                    bf16x8 bv8 = *(const bf16x8*)&Vs[n*16 + lr][(half*2 + kc)*32 + quad*8];
                    o_acc[0][n] = MFMA_BF16(ap0, bv8, o_acc[0][n]);
                    o_acc[1][n] = MFMA_BF16(ap1, bv8, o_acc[1][n]);
                }
            }
        }
    }

    // epilogue: o / l, write bf16 [b,s,d]
    #pragma unroll
    for (int i = 0; i < 2; i++)
        #pragma unroll
        for (int n = 0; n < 4; n++)
            #pragma unroll
            for (int r = 0; r < 4; r++) {
                const float v = o_acc[i][n][r] / l_i[i][r];
                const int s   = qt*128 + wave*32 + i*16 + quad*4 + r;
                const int col = h*64 + n*16 + lr;
                o_ws[((size_t)b_ * 2048 + s) * 1024 + col] = (bf16)v;
            }
}

// ---------------------------------------------------------------------------
// Kernel 3: output projection.  out[m,n] = sum_k o[m,k]*Wo[n,k] + bo[n], fp32 out
// ---------------------------------------------------------------------------
__global__ __launch_bounds__(256)
void out_gemm(const bf16* __restrict__ o_ws,
              const float* __restrict__ Wo, const float* __restrict__ bo,
              float* __restrict__ out)
{
    __shared__ bf16 As[128][40];
    __shared__ bf16 Bs[128][40];

    const int m0 = blockIdx.x * 128;
    const int n0 = blockIdx.y * 128;
    const int t    = threadIdx.x;
    const int wave = t >> 6;
    const int lane = t & 63;
    const int lr   = lane & 15;
    const int quad = lane >> 4;
    const int wm = (wave & 1) * 64;
    const int wn = (wave >> 1) * 64;
    const int srow = t >> 1;
    const int scol = (t & 1) * 16;

    f32x4 acc[4][4] = {};

    for (int k0 = 0; k0 < 1024; k0 += 32) {
        const bf16*  asrc = o_ws + (size_t)(m0 + srow) * 1024 + k0 + scol;
        const float* bsrc = Wo   + (size_t)(n0 + srow) * 1024 + k0 + scol;
        *(bf16x8*)&As[srow][scol]     = ((const bf16x8*)asrc)[0];
        *(bf16x8*)&As[srow][scol + 8] = ((const bf16x8*)asrc)[1];
        float4 b0 = ((const float4*)bsrc)[0];
        float4 b1 = ((const float4*)bsrc)[1];
        float4 b2 = ((const float4*)bsrc)[2];
        float4 b3 = ((const float4*)bsrc)[3];
        bf16x8 pb0 = {(bf16)b0.x,(bf16)b0.y,(bf16)b0.z,(bf16)b0.w,(bf16)b1.x,(bf16)b1.y,(bf16)b1.z,(bf16)b1.w};
        bf16x8 pb1 = {(bf16)b2.x,(bf16)b2.y,(bf16)b2.z,(bf16)b2.w,(bf16)b3.x,(bf16)b3.y,(bf16)b3.z,(bf16)b3.w};
        *(bf16x8*)&Bs[srow][scol]     = pb0;
        *(bf16x8*)&Bs[srow][scol + 8] = pb1;
        __syncthreads();

        bf16x8 af[4], bfr[4];
        #pragma unroll
        for (int i = 0; i < 4; i++) af[i]  = *(const bf16x8*)&As[wm + i*16 + lr][quad*8];
        #pragma unroll
        for (int j = 0; j < 4; j++) bfr[j] = *(const bf16x8*)&Bs[wn + j*16 + lr][quad*8];
        #pragma unroll
        for (int i = 0; i < 4; i++)
            #pragma unroll
            for (int j = 0; j < 4; j++)
                acc[i][j] = MFMA_BF16(af[i], bfr[j], acc[i][j]);
        __syncthreads();
    }

    #pragma unroll
    for (int j = 0; j < 4; j++) {
        const int col = n0 + wn + j * 16 + lr;
        const float bb = bo[col];
        #pragma unroll
        for (int i = 0; i < 4; i++) {
            #pragma unroll
            for (int r = 0; r < 4; r++) {
                const int row = m0 + wm + i * 16 + quad * 4 + r;
                out[(size_t)row * 1024 + col] = acc[i][j][r] + bb;
            }
        }
    }
}

extern "C" void kernel_launch(void* const* d_in, const int* in_sizes, int n_in,
                              void* d_out, int out_size, void* d_ws, size_t ws_size,
                              hipStream_t stream) {
    (void)in_sizes; (void)n_in; (void)out_size; (void)ws_size;
    const float* x  = (const float*)d_in[0];
    const float* Wq = (const float*)d_in[1];
    const float* bq = (const float*)d_in[2];
    const float* Wk = (const float*)d_in[3];
    const float* bk = (const float*)d_in[4];
    const float* Wv = (const float*)d_in[5];
    const float* bv = (const float*)d_in[6];
    const float* Wo = (const float*)d_in[7];
    const float* bo = (const float*)d_in[8];
    float* out = (float*)d_out;

    char* ws = (char*)d_ws;
    bf16* q_ws = (bf16*)(ws);
    bf16* k_ws = (bf16*)(ws + (size_t)8  * 1024 * 1024);
    bf16* v_ws = (bf16*)(ws + (size_t)16 * 1024 * 1024);
    bf16* o_ws = (bf16*)(ws + (size_t)24 * 1024 * 1024);

    hipLaunchKernelGGL(qkv_gemm, dim3(32, 8, 3), dim3(256), 0, stream,
                       x, Wq, bq, Wk, bk, Wv, bv, q_ws, k_ws, v_ws);
    hipLaunchKernelGGL(attn, dim3(16, 32), dim3(256), 0, stream,
                       q_ws, k_ws, v_ws, o_ws);
    hipLaunchKernelGGL(out_gemm, dim3(32, 8), dim3(256), 0, stream,
                       o_ws, Wo, bo, out);
}

// Round 3
// 251.503 us; speedup vs baseline: 1.2582x; 1.1685x over previous
//
#include <hip/hip_runtime.h>

// MHA: B=2 S=2048 D=1024 H=16 DH=64.  All GEMMs bf16 MFMA, fp32 acc.
// R3: (a) attn restructured to S^T = K*Q^T so softmaxed P fragment is directly
//     the A-operand of a 16x16x16 PV MFMA (no P LDS round-trip); 64-row Q
//     blocks -> grid 1024 -> 4 blocks/CU. (b) inputs pre-converted to bf16 so
//     GEMM staging is pure bf16x8 (no fp32 cvt in K-loop). (c) qkv V epilogue
//     transposed through LDS -> coalesced stores (was 2B/4KB-stride scatter).
// ws: xb 8MB @0 | wq/wk/wv/wo bf16 2MB each @8/10/12/14MB | q 8MB @16MB |
//     k 8MB @24MB | v^T 8MB @32MB [b,h,dh,s] | o 8MB @40MB  (needs 48MB ws)

typedef __bf16 bf16;
typedef bf16 bf16x8 __attribute__((ext_vector_type(8)));
typedef bf16 bf16x4 __attribute__((ext_vector_type(4)));
typedef short s16x4 __attribute__((ext_vector_type(4)));
typedef float f32x4 __attribute__((ext_vector_type(4)));

#define MFMA32(a, b, c) __builtin_amdgcn_mfma_f32_16x16x32_bf16(a, b, c, 0, 0, 0)

#if __has_builtin(__builtin_amdgcn_mfma_f32_16x16x16bf16_1k)
#define HAVE_MFMA16 1
#define MFMA16(a, b, c) __builtin_amdgcn_mfma_f32_16x16x16bf16_1k(a, b, c, 0, 0, 0)
#else
#define HAVE_MFMA16 0
#endif

union pk4 { bf16x4 h; s16x4 s; unsigned int d[2]; };

// ---------------------------------------------------------------------------
// Kernel 0: fp32 -> bf16 conversion of x and the four weight matrices.
// 8M elements total, 1 float4 per thread.
// ---------------------------------------------------------------------------
__global__ __launch_bounds__(256)
void cvt_bf16(const float* __restrict__ x,  const float* __restrict__ Wq,
              const float* __restrict__ Wk, const float* __restrict__ Wv,
              const float* __restrict__ Wo,
              bf16* __restrict__ xb, bf16* __restrict__ wqb, bf16* __restrict__ wkb,
              bf16* __restrict__ wvb, bf16* __restrict__ wob)
{
    const int idx = blockIdx.x * 256 + threadIdx.x;   // float4 index
    const float* src; bf16* dst; int off;
    if (idx < 1048576) { src = x; dst = xb; off = idx; }
    else {
        const int r = idx - 1048576;
        const int seg = r >> 18;          // 0..3  (262144 float4 per W)
        off = r & 262143;
        src = (seg == 0) ? Wq : (seg == 1) ? Wk : (seg == 2) ? Wv : Wo;
        dst = (seg == 0) ? wqb : (seg == 1) ? wkb : (seg == 2) ? wvb : wob;
    }
    const float4 v = ((const float4*)src)[off];
    bf16x4 o = {(bf16)v.x, (bf16)v.y, (bf16)v.z, (bf16)v.w};
    *(bf16x4*)(dst + (size_t)off * 4) = o;
}

// ---------------------------------------------------------------------------
// Kernel 1: fused QKV projection (bf16 inputs).  C[m,n] = x[m,:] . W[n,:] + b
// grid (32 Mtiles, 8 Ntiles, 3 matrices), 256 threads.
// ---------------------------------------------------------------------------
__global__ __launch_bounds__(256)
void qkv_gemm(const bf16* __restrict__ xb,
              const bf16* __restrict__ wqb, const float* __restrict__ bq,
              const bf16* __restrict__ wkb, const float* __restrict__ bk,
              const bf16* __restrict__ wvb, const float* __restrict__ bv,
              bf16* __restrict__ q_ws, bf16* __restrict__ k_ws, bf16* __restrict__ v_ws)
{
    const int z = blockIdx.z;
    const bf16*  W    = (z == 0) ? wqb : (z == 1) ? wkb : wvb;
    const float* bias = (z == 0) ? bq  : (z == 1) ? bk  : bv;

    __shared__ bf16 As[128][40];
    __shared__ bf16 Bs[128][40];
    __shared__ bf16 Vt[64][132];   // V-transpose staging (z==2 epilogue only)

    const int m0 = blockIdx.x * 128;
    const int n0 = blockIdx.y * 128;
    const int t    = threadIdx.x;
    const int wave = t >> 6;
    const int lane = t & 63;
    const int lr   = lane & 15;
    const int quad = lane >> 4;
    const int wm = (wave & 1) * 64;
    const int wn = (wave >> 1) * 64;

    f32x4 acc[4][4] = {};

    for (int k0 = 0; k0 < 1024; k0 += 32) {
        #pragma unroll
        for (int u = 0; u < 2; u++) {
            const int c = t + u * 256;          // 0..511
            const int row = c >> 2, coloff = (c & 3) * 8;
            *(bf16x8*)&As[row][coloff] =
                *(const bf16x8*)(xb + (size_t)(m0 + row) * 1024 + k0 + coloff);
            *(bf16x8*)&Bs[row][coloff] =
                *(const bf16x8*)(W + (size_t)(n0 + row) * 1024 + k0 + coloff);
        }
        __syncthreads();

        bf16x8 af[4], bfr[4];
        #pragma unroll
        for (int i = 0; i < 4; i++) af[i]  = *(const bf16x8*)&As[wm + i*16 + lr][quad*8];
        #pragma unroll
        for (int j = 0; j < 4; j++) bfr[j] = *(const bf16x8*)&Bs[wn + j*16 + lr][quad*8];
        #pragma unroll
        for (int i = 0; i < 4; i++)
            #pragma unroll
            for (int j = 0; j < 4; j++)
                acc[i][j] = MFMA32(af[i], bfr[j], acc[i][j]);
        __syncthreads();
    }

    if (z < 2) {
        // q (pre-scaled by 0.125) and k: head-major [b,h,s,dh]
        bf16* dstb = (z == 0) ? q_ws : k_ws;
        const float sc = (z == 0) ? 0.125f : 1.0f;
        #pragma unroll
        for (int j = 0; j < 4; j++) {
            const int col = n0 + wn + j * 16 + lr;
            const float bb = bias[col];
            const int h  = col >> 6;
            const int dh = col & 63;
            #pragma unroll
            for (int i = 0; i < 4; i++)
                #pragma unroll
                for (int r = 0; r < 4; r++) {
                    const int row = m0 + wm + i * 16 + quad * 4 + r;
                    const int bi = row >> 11, si = row & 2047;
                    dstb[(((size_t)bi * 16 + h) * 2048 + si) * 64 + dh] =
                        (bf16)((acc[i][j][r] + bb) * sc);
                }
        }
    } else {
        // v: transpose each 64-col half through LDS, then coalesced stores
        const int bi = m0 >> 11, si0 = m0 & 2047;
        #pragma unroll
        for (int ph = 0; ph < 2; ph++) {
            if ((wave >> 1) == ph) {
                #pragma unroll
                for (int j = 0; j < 4; j++) {
                    const float bb = bias[n0 + ph * 64 + j * 16 + lr];
                    #pragma unroll
                    for (int i = 0; i < 4; i++)
                        #pragma unroll
                        for (int r = 0; r < 4; r++)
                            Vt[j * 16 + lr][wm + i * 16 + quad * 4 + r] =
                                (bf16)(acc[i][j][r] + bb);
                }
            }
            __syncthreads();
            // 64 feature-rows x 128 si, 2B: 4 threads/row, 32 si each
            const int c  = t >> 2;             // local feature 0..63
            const int sc_ = (t & 3) * 32;
            const int col = n0 + ph * 64 + c;
            const int h = col >> 6, dh = col & 63;
            bf16* dst = v_ws + (((size_t)bi * 16 + h) * 64 + dh) * 2048 + si0 + sc_;
            #pragma unroll
            for (int e = 0; e < 4; e++)
                *(bf16x8*)(dst + e * 8) = *(const bf16x8*)&Vt[c][sc_ + e * 8];
            __syncthreads();
        }
    }
}

// ---------------------------------------------------------------------------
// Kernel 2: flash attention, S^T formulation.  grid (32 q-tiles, 32 b*h).
// Block = 64 Q rows; wave owns 16 rows (qrow = lane&15 in S^T space).
// S^T = K.Q^T via MFMA(A=K, B=Q): D[row=key=quad*4+r][col=qrow=lane&15].
// That C-layout IS the A-layout of 16x16x16 MFMA -> PV straight from regs.
// LDS: Ks 18KB + Vs 17KB = 35KB -> 4 blocks/CU.
// ---------------------------------------------------------------------------
__global__ __launch_bounds__(256, 4)
void attn(const bf16* __restrict__ q_ws, const bf16* __restrict__ k_ws,
          const bf16* __restrict__ v_ws, bf16* __restrict__ o_ws)
{
    const int qt = blockIdx.x;
    const int bh = blockIdx.y;           // b*16+h
    const int b_ = bh >> 4, h = bh & 15;

    const bf16* qbase = q_ws + (size_t)bh * 2048 * 64;
    const bf16* kbase = k_ws + (size_t)bh * 2048 * 64;
    const bf16* vbase = v_ws + (size_t)bh * 64 * 2048;  // [64][2048] V^T

    __shared__ bf16 Ks[128][72];     // [key][feat]
    __shared__ bf16 Vs[64][136];     // [feat][key]

    const int t    = threadIdx.x;
    const int wave = t >> 6;
    const int lane = t & 63;
    const int lr   = lane & 15;
    const int quad = lane >> 4;

    // Q fragments (pre-scaled by 0.125): B-operand, n=qrow=lr, k=feat
    bf16x8 aq[2];
    #pragma unroll
    for (int kc = 0; kc < 2; kc++)
        aq[kc] = *(const bf16x8*)(qbase +
            (size_t)(qt*64 + wave*16 + lr) * 64 + kc*32 + quad*8);

    float m_i = -1e30f, l_i = 0.f;       // stats for qrow = lr (all quads hold copies)
    f32x4 o_acc[4] = {};                 // rows qrow=quad*4+r, cols d=n*16+lr
    const float C = 1.44269504f;         // log2(e)

    for (int kt = 0; kt < 16; kt++) {
        __syncthreads();
        #pragma unroll
        for (int u = 0; u < 4; u++) {
            const int c = t + u * 256;          // 0..1023
            *(bf16x8*)&Ks[c >> 3][(c & 7) * 8] =
                *(const bf16x8*)(kbase + (size_t)kt * 128 * 64 + c * 8);
            const int d = c >> 4, off = (c & 15) * 8;
            *(bf16x8*)&Vs[d][off] =
                *(const bf16x8*)(vbase + (size_t)d * 2048 + kt*128 + off);
        }
        __syncthreads();

        // S^T: 8 key-frags x 16 qrows
        f32x4 sacc[8];
        #pragma unroll
        for (int j = 0; j < 8; j++) {
            bf16x8 kf0 = *(const bf16x8*)&Ks[j*16 + lr][quad*8];
            bf16x8 kf1 = *(const bf16x8*)&Ks[j*16 + lr][32 + quad*8];
            f32x4 a = {0.f, 0.f, 0.f, 0.f};
            a = MFMA32(kf0, aq[0], a);
            a = MFMA32(kf1, aq[1], a);
            sacc[j] = a;
        }

        // online softmax for qrow = lr: lane holds 32 of 128 keys; rest via quads
        float m = -1e30f;
        #pragma unroll
        for (int j = 0; j < 8; j++)
            #pragma unroll
            for (int r = 0; r < 4; r++) m = fmaxf(m, sacc[j][r]);
        m = fmaxf(m, __shfl_xor(m, 16));
        m = fmaxf(m, __shfl_xor(m, 32));
        const float nm = fmaxf(m_i, m);
        const float al = exp2f((m_i - nm) * C);
        m_i = nm;
        const float nmc = nm * C;
        float rs = 0.f;
        #pragma unroll
        for (int j = 0; j < 8; j++)
            #pragma unroll
            for (int r = 0; r < 4; r++) {
                const float p = exp2f(fmaf(sacc[j][r], C, -nmc));
                sacc[j][r] = p;
                rs += p;
            }
        rs += __shfl_xor(rs, 16);
        rs += __shfl_xor(rs, 32);
        l_i = l_i * al + rs;

        // rescale O (rows = quad*4+r; alpha lives at lane quad*4+r)
        float alr[4];
        #pragma unroll
        for (int r = 0; r < 4; r++) alr[r] = __shfl(al, quad * 4 + r);
        #pragma unroll
        for (int n = 0; n < 4; n++)
            #pragma unroll
            for (int r = 0; r < 4; r++) o_acc[n][r] *= alr[r];

#if HAVE_MFMA16
        // PV: P-frag = softmaxed sacc directly (A[m=lr][k=quad*4+j])
        #pragma unroll
        for (int j = 0; j < 8; j++) {
            pk4 pf;
            pf.h = bf16x4{(bf16)sacc[j][0], (bf16)sacc[j][1],
                          (bf16)sacc[j][2], (bf16)sacc[j][3]};
            #pragma unroll
            for (int n = 0; n < 4; n++) {
                pk4 bf_;
                *(unsigned long long*)bf_.d =
                    *(const unsigned long long*)&Vs[n*16 + lr][j*16 + quad*4];
                o_acc[n] = MFMA16(pf.s, bf_.s, o_acc[n]);
            }
        }
#else
        // Fallback: build K=32 A-frags via shuffles, use 16x16x32 MFMA.
        unsigned int u0[8], u1[8];
        #pragma unroll
        for (int j = 0; j < 8; j++) {
            pk4 pf;
            pf.h = bf16x4{(bf16)sacc[j][0], (bf16)sacc[j][1],
                          (bf16)sacc[j][2], (bf16)sacc[j][3]};
            u0[j] = pf.d[0]; u1[j] = pf.d[1];
        }
        const int src0 = 32 * (quad & 1) + lr;
        const int src1 = src0 + 16;
        #pragma unroll
        for (int c = 0; c < 4; c++) {
            unsigned int w0a = __shfl(u0[2*c], src0),   w0b = __shfl(u0[2*c+1], src0);
            unsigned int w1a = __shfl(u1[2*c], src0),   w1b = __shfl(u1[2*c+1], src0);
            unsigned int w2a = __shfl(u0[2*c], src1),   w2b = __shfl(u0[2*c+1], src1);
            unsigned int w3a = __shfl(u1[2*c], src1),   w3b = __shfl(u1[2*c+1], src1);
            unsigned int fr[4];
            fr[0] = (quad >= 2) ? w0b : w0a;
            fr[1] = (quad >= 2) ? w1b : w1a;
            fr[2] = (quad >= 2) ? w2b : w2a;
            fr[3] = (quad >= 2) ? w3b : w3a;
            bf16x8 pf8 = *(bf16x8*)fr;
            #pragma unroll
            for (int n = 0; n < 4; n++) {
                bf16x8 bv8 = *(const bf16x8*)&Vs[n*16 + lr][c*32 + quad*8];
                o_acc[n] = MFMA32(pf8, bv8, o_acc[n]);
            }
        }
#endif
    }

    // epilogue: divide by l (per-row, gathered), write bf16 [b,s,d]
    float lv[4];
    #pragma unroll
    for (int r = 0; r < 4; r++) lv[r] = __shfl(l_i, quad * 4 + r);
    #pragma unroll
    for (int n = 0; n < 4; n++)
        #pragma unroll
        for (int r = 0; r < 4; r++) {
            const int s   = qt*64 + wave*16 + quad*4 + r;
            const int col = h*64 + n*16 + lr;
            o_ws[((size_t)b_ * 2048 + s) * 1024 + col] = (bf16)(o_acc[n][r] / lv[r]);
        }
}

// ---------------------------------------------------------------------------
// Kernel 3: output projection.  out[m,n] = o[m,:] . Wo[n,:] + bo[n], fp32 out
// ---------------------------------------------------------------------------
__global__ __launch_bounds__(256)
void out_gemm(const bf16* __restrict__ o_ws,
              const bf16* __restrict__ wob, const float* __restrict__ bo,
              float* __restrict__ out)
{
    __shared__ bf16 As[128][40];
    __shared__ bf16 Bs[128][40];

    const int m0 = blockIdx.x * 128;
    const int n0 = blockIdx.y * 128;
    const int t    = threadIdx.x;
    const int wave = t >> 6;
    const int lane = t & 63;
    const int lr   = lane & 15;
    const int quad = lane >> 4;
    const int wm = (wave & 1) * 64;
    const int wn = (wave >> 1) * 64;

    f32x4 acc[4][4] = {};

    for (int k0 = 0; k0 < 1024; k0 += 32) {
        #pragma unroll
        for (int u = 0; u < 2; u++) {
            const int c = t + u * 256;
            const int row = c >> 2, coloff = (c & 3) * 8;
            *(bf16x8*)&As[row][coloff] =
                *(const bf16x8*)(o_ws + (size_t)(m0 + row) * 1024 + k0 + coloff);
            *(bf16x8*)&Bs[row][coloff] =
                *(const bf16x8*)(wob + (size_t)(n0 + row) * 1024 + k0 + coloff);
        }
        __syncthreads();

        bf16x8 af[4], bfr[4];
        #pragma unroll
        for (int i = 0; i < 4; i++) af[i]  = *(const bf16x8*)&As[wm + i*16 + lr][quad*8];
        #pragma unroll
        for (int j = 0; j < 4; j++) bfr[j] = *(const bf16x8*)&Bs[wn + j*16 + lr][quad*8];
        #pragma unroll
        for (int i = 0; i < 4; i++)
            #pragma unroll
            for (int j = 0; j < 4; j++)
                acc[i][j] = MFMA32(af[i], bfr[j], acc[i][j]);
        __syncthreads();
    }

    #pragma unroll
    for (int j = 0; j < 4; j++) {
        const int col = n0 + wn + j * 16 + lr;
        const float bb = bo[col];
        #pragma unroll
        for (int i = 0; i < 4; i++)
            #pragma unroll
            for (int r = 0; r < 4; r++) {
                const int row = m0 + wm + i * 16 + quad * 4 + r;
                out[(size_t)row * 1024 + col] = acc[i][j][r] + bb;
            }
    }
}

extern "C" void kernel_launch(void* const* d_in, const int* in_sizes, int n_in,
                              void* d_out, int out_size, void* d_ws, size_t ws_size,
                              hipStream_t stream) {
    (void)in_sizes; (void)n_in; (void)out_size; (void)ws_size;
    const float* x  = (const float*)d_in[0];
    const float* Wq = (const float*)d_in[1];
    const float* bq = (const float*)d_in[2];
    const float* Wk = (const float*)d_in[3];
    const float* bk = (const float*)d_in[4];
    const float* Wv = (const float*)d_in[5];
    const float* bv = (const float*)d_in[6];
    const float* Wo = (const float*)d_in[7];
    const float* bo = (const float*)d_in[8];
    float* out = (float*)d_out;

    char* ws = (char*)d_ws;
    const size_t MB = 1024 * 1024;
    bf16* xb   = (bf16*)(ws);
    bf16* wqb  = (bf16*)(ws + 8 * MB);
    bf16* wkb  = (bf16*)(ws + 10 * MB);
    bf16* wvb  = (bf16*)(ws + 12 * MB);
    bf16* wob  = (bf16*)(ws + 14 * MB);
    bf16* q_ws = (bf16*)(ws + 16 * MB);
    bf16* k_ws = (bf16*)(ws + 24 * MB);
    bf16* v_ws = (bf16*)(ws + 32 * MB);
    bf16* o_ws = (bf16*)(ws + 40 * MB);

    hipLaunchKernelGGL(cvt_bf16, dim3(8192), dim3(256), 0, stream,
                       x, Wq, Wk, Wv, Wo, xb, wqb, wkb, wvb, wob);
    hipLaunchKernelGGL(qkv_gemm, dim3(32, 8, 3), dim3(256), 0, stream,
                       xb, wqb, bq, wkb, bk, wvb, bv, q_ws, k_ws, v_ws);
    hipLaunchKernelGGL(attn, dim3(32, 32), dim3(256), 0, stream,
                       q_ws, k_ws, v_ws, o_ws);
    hipLaunchKernelGGL(out_gemm, dim3(32, 8), dim3(256), 0, stream,
                       o_ws, wob, bo, out);
}

// Round 4
// 243.774 us; speedup vs baseline: 1.2981x; 1.0317x over previous
//
#include <hip/hip_runtime.h>

// MHA: B=2 S=2048 D=1024 H=16 DH=64.  All GEMMs bf16 MFMA, fp32 acc.
// R4: (a) GEMMs use global_load_lds width=16 staging into unpadded [128][32]
//     LDS (m97 structure; no VGPR round-trip). (b) attn accumulates O^T =
//     V^T . P^T so the softmaxed sacc fragment is directly the B-operand and
//     all softmax stats stay per-lane (no alpha/l shuffle gathers at all).
// ws: xb 8MB @0 | wq/wk/wv/wo bf16 2MB each @8/10/12/14MB | q 8MB @16MB |
//     k 8MB @24MB | v^T 8MB @32MB [b,h,dh,s] | o 8MB @40MB  (needs 48MB ws)

typedef __bf16 bf16;
typedef bf16 bf16x8 __attribute__((ext_vector_type(8)));
typedef bf16 bf16x4 __attribute__((ext_vector_type(4)));
typedef short s16x4 __attribute__((ext_vector_type(4)));
typedef float f32x4 __attribute__((ext_vector_type(4)));

#define MFMA32(a, b, c) __builtin_amdgcn_mfma_f32_16x16x32_bf16(a, b, c, 0, 0, 0)

#if __has_builtin(__builtin_amdgcn_mfma_f32_16x16x16bf16_1k)
#define HAVE_MFMA16 1
#define MFMA16(a, b, c) __builtin_amdgcn_mfma_f32_16x16x16bf16_1k(a, b, c, 0, 0, 0)
#else
#define HAVE_MFMA16 0
#endif

// async global->LDS, 16B per lane; LDS dst must be wave-uniform base + lane*16
#define GLL(g, l) __builtin_amdgcn_global_load_lds(                              \
    (const __attribute__((address_space(1))) void*)(const void*)(g),             \
    (__attribute__((address_space(3))) void*)(void*)(l), 16, 0, 0)

union pk4 { bf16x4 h; s16x4 s; unsigned int d[2]; };

// ---------------------------------------------------------------------------
// Kernel 0: fp32 -> bf16 conversion of x and the four weight matrices.
// ---------------------------------------------------------------------------
__global__ __launch_bounds__(256)
void cvt_bf16(const float* __restrict__ x,  const float* __restrict__ Wq,
              const float* __restrict__ Wk, const float* __restrict__ Wv,
              const float* __restrict__ Wo,
              bf16* __restrict__ xb, bf16* __restrict__ wqb, bf16* __restrict__ wkb,
              bf16* __restrict__ wvb, bf16* __restrict__ wob)
{
    const int idx = blockIdx.x * 256 + threadIdx.x;   // float4 index
    const float* src; bf16* dst; int off;
    if (idx < 1048576) { src = x; dst = xb; off = idx; }
    else {
        const int r = idx - 1048576;
        const int seg = r >> 18;          // 0..3  (262144 float4 per W)
        off = r & 262143;
        src = (seg == 0) ? Wq : (seg == 1) ? Wk : (seg == 2) ? Wv : Wo;
        dst = (seg == 0) ? wqb : (seg == 1) ? wkb : (seg == 2) ? wvb : wob;
    }
    const float4 v = ((const float4*)src)[off];
    bf16x4 o = {(bf16)v.x, (bf16)v.y, (bf16)v.z, (bf16)v.w};
    *(bf16x4*)(dst + (size_t)off * 4) = o;
}

// ---------------------------------------------------------------------------
// Kernel 1: fused QKV projection (bf16 inputs).  C[m,n] = x[m,:] . W[n,:] + b
// grid (32 Mtiles, 8 Ntiles, 3 matrices), 256 threads.  m97-style staging.
// ---------------------------------------------------------------------------
__global__ __launch_bounds__(256)
void qkv_gemm(const bf16* __restrict__ xb,
              const bf16* __restrict__ wqb, const float* __restrict__ bq,
              const bf16* __restrict__ wkb, const float* __restrict__ bk,
              const bf16* __restrict__ wvb, const float* __restrict__ bv,
              bf16* __restrict__ q_ws, bf16* __restrict__ k_ws, bf16* __restrict__ v_ws)
{
    const int z = blockIdx.z;
    const bf16*  W    = (z == 0) ? wqb : (z == 1) ? wkb : wvb;
    const float* bias = (z == 0) ? bq  : (z == 1) ? bk  : bv;

    __shared__ bf16 As[128][32];   // unpadded: required by global_load_lds layout
    __shared__ bf16 Bs[128][32];
    __shared__ bf16 Vt[64][132];   // V-transpose staging (z==2 epilogue only)

    const int m0 = blockIdx.x * 128;
    const int n0 = blockIdx.y * 128;
    const int t    = threadIdx.x;
    const int wave = t >> 6;
    const int lane = t & 63;
    const int lr   = lane & 15;
    const int quad = lane >> 4;
    const int wm = (wave & 1) * 64;
    const int wn = (wave >> 1) * 64;

    // staging geometry: wave w stages rows [32w,32w+32), 2 instrs of 16 rows,
    // lane -> row 32w+16u+(lane>>2), col (lane&3)*8; LDS = wave base + lane*16
    const int srow = wave * 32 + (lane >> 2);
    const int scol = (lane & 3) * 8;
    const bf16* ga0 = xb + (size_t)(m0 + srow) * 1024 + scol;
    const bf16* ga1 = xb + (size_t)(m0 + srow + 16) * 1024 + scol;
    const bf16* gb0 = W  + (size_t)(n0 + srow) * 1024 + scol;
    const bf16* gb1 = W  + (size_t)(n0 + srow + 16) * 1024 + scol;
    bf16* la0 = &As[srow][scol];
    bf16* la1 = &As[srow + 16][scol];
    bf16* lb0 = &Bs[srow][scol];
    bf16* lb1 = &Bs[srow + 16][scol];

    f32x4 acc[4][4] = {};

    for (int k0 = 0; k0 < 1024; k0 += 32) {
        GLL(ga0 + k0, la0);
        GLL(ga1 + k0, la1);
        GLL(gb0 + k0, lb0);
        GLL(gb1 + k0, lb1);
        __syncthreads();

        bf16x8 af[4], bfr[4];
        #pragma unroll
        for (int i = 0; i < 4; i++) af[i]  = *(const bf16x8*)&As[wm + i*16 + lr][quad*8];
        #pragma unroll
        for (int j = 0; j < 4; j++) bfr[j] = *(const bf16x8*)&Bs[wn + j*16 + lr][quad*8];
        #pragma unroll
        for (int i = 0; i < 4; i++)
            #pragma unroll
            for (int j = 0; j < 4; j++)
                acc[i][j] = MFMA32(af[i], bfr[j], acc[i][j]);
        __syncthreads();
    }

    if (z < 2) {
        // q (pre-scaled by 0.125) and k: head-major [b,h,s,dh]
        bf16* dstb = (z == 0) ? q_ws : k_ws;
        const float sc = (z == 0) ? 0.125f : 1.0f;
        #pragma unroll
        for (int j = 0; j < 4; j++) {
            const int col = n0 + wn + j * 16 + lr;
            const float bb = bias[col];
            const int h  = col >> 6;
            const int dh = col & 63;
            #pragma unroll
            for (int i = 0; i < 4; i++)
                #pragma unroll
                for (int r = 0; r < 4; r++) {
                    const int row = m0 + wm + i * 16 + quad * 4 + r;
                    const int bi = row >> 11, si = row & 2047;
                    dstb[(((size_t)bi * 16 + h) * 2048 + si) * 64 + dh] =
                        (bf16)((acc[i][j][r] + bb) * sc);
                }
        }
    } else {
        // v: transpose each 64-col half through LDS, then coalesced stores
        const int bi = m0 >> 11, si0 = m0 & 2047;
        #pragma unroll
        for (int ph = 0; ph < 2; ph++) {
            if ((wave >> 1) == ph) {
                #pragma unroll
                for (int j = 0; j < 4; j++) {
                    const float bb = bias[n0 + ph * 64 + j * 16 + lr];
                    #pragma unroll
                    for (int i = 0; i < 4; i++)
                        #pragma unroll
                        for (int r = 0; r < 4; r++)
                            Vt[j * 16 + lr][wm + i * 16 + quad * 4 + r] =
                                (bf16)(acc[i][j][r] + bb);
                }
            }
            __syncthreads();
            const int c  = t >> 2;             // local feature 0..63
            const int sc_ = (t & 3) * 32;
            const int col = n0 + ph * 64 + c;
            const int h = col >> 6, dh = col & 63;
            bf16* dst = v_ws + (((size_t)bi * 16 + h) * 64 + dh) * 2048 + si0 + sc_;
            #pragma unroll
            for (int e = 0; e < 4; e++)
                *(bf16x8*)(dst + e * 8) = *(const bf16x8*)&Vt[c][sc_ + e * 8];
            __syncthreads();
        }
    }
}

// ---------------------------------------------------------------------------
// Kernel 2: flash attention, fully transposed.  grid (32 q-tiles, 32 b*h).
// S^T = K.Q^T (C-layout: key=quad*4+r, qrow=lane&15).  softmaxed sacc IS the
// B-operand of 16x16x16 MFMA, so O^T = V^T.P^T accumulates with qrow=lane&15
// columns -> all per-row stats (m,l,alpha) are per-lane scalars. No shuffles
// except the 4 cross-quad reductions (2 on critical path).
// LDS: Ks 18KB + Vs 17KB = 35KB -> 4 blocks/CU.
// ---------------------------------------------------------------------------
__global__ __launch_bounds__(256, 4)
void attn(const bf16* __restrict__ q_ws, const bf16* __restrict__ k_ws,
          const bf16* __restrict__ v_ws, bf16* __restrict__ o_ws)
{
    const int qt = blockIdx.x;
    const int bh = blockIdx.y;           // b*16+h
    const int b_ = bh >> 4, h = bh & 15;

    const bf16* qbase = q_ws + (size_t)bh * 2048 * 64;
    const bf16* kbase = k_ws + (size_t)bh * 2048 * 64;
    const bf16* vbase = v_ws + (size_t)bh * 64 * 2048;  // [64][2048] V^T

    __shared__ bf16 Ks[128][72];     // [key][feat]   (padded: VGPR staging)
    __shared__ bf16 Vs[64][136];     // [feat][key]

    const int t    = threadIdx.x;
    const int wave = t >> 6;
    const int lane = t & 63;
    const int lr   = lane & 15;
    const int quad = lane >> 4;

    // Q fragments (pre-scaled by 0.125): B-operand of QK^T, n=qrow=lr
    bf16x8 aq[2];
    #pragma unroll
    for (int kc = 0; kc < 2; kc++)
        aq[kc] = *(const bf16x8*)(qbase +
            (size_t)(qt*64 + wave*16 + lr) * 64 + kc*32 + quad*8);

    float m_i = -1e30f, l_i = 0.f;       // stats for qrow = lr (per-lane)
    f32x4 o_accT[4] = {};                // O^T: rows feat=fb*16+quad*4+r, cols qrow=lr
    const float C = 1.44269504f;         // log2(e)

    for (int kt = 0; kt < 16; kt++) {
        __syncthreads();
        #pragma unroll
        for (int u = 0; u < 4; u++) {
            const int c = t + u * 256;          // 0..1023
            *(bf16x8*)&Ks[c >> 3][(c & 7) * 8] =
                *(const bf16x8*)(kbase + (size_t)kt * 128 * 64 + c * 8);
            const int d = c >> 4, off = (c & 15) * 8;
            *(bf16x8*)&Vs[d][off] =
                *(const bf16x8*)(vbase + (size_t)d * 2048 + kt*128 + off);
        }
        __syncthreads();

        // S^T: 8 key-frags x 16 qrows
        f32x4 sacc[8];
        #pragma unroll
        for (int j = 0; j < 8; j++) {
            bf16x8 kf0 = *(const bf16x8*)&Ks[j*16 + lr][quad*8];
            bf16x8 kf1 = *(const bf16x8*)&Ks[j*16 + lr][32 + quad*8];
            f32x4 a = {0.f, 0.f, 0.f, 0.f};
            a = MFMA32(kf0, aq[0], a);
            a = MFMA32(kf1, aq[1], a);
            sacc[j] = a;
        }

        // online softmax for qrow = lr (lane holds 32 of 128 keys)
        float m = -1e30f;
        #pragma unroll
        for (int j = 0; j < 8; j++)
            #pragma unroll
            for (int r = 0; r < 4; r++) m = fmaxf(m, sacc[j][r]);
        m = fmaxf(m, __shfl_xor(m, 16));
        m = fmaxf(m, __shfl_xor(m, 32));
        const float nm = fmaxf(m_i, m);
        const float al = exp2f((m_i - nm) * C);
        m_i = nm;
        const float nmc = nm * C;
        float rs = 0.f;
        #pragma unroll
        for (int j = 0; j < 8; j++)
            #pragma unroll
            for (int r = 0; r < 4; r++) {
                const float p = exp2f(fmaf(sacc[j][r], C, -nmc));
                sacc[j][r] = p;
                rs += p;
            }
        // rescale O^T: alpha is a per-lane scalar (cols are qrow=lr)
        #pragma unroll
        for (int n = 0; n < 4; n++)
            #pragma unroll
            for (int r = 0; r < 4; r++) o_accT[n][r] *= al;
        // l update (off the critical path of PV)
        rs += __shfl_xor(rs, 16);
        rs += __shfl_xor(rs, 32);
        l_i = l_i * al + rs;

#if HAVE_MFMA16
        // O^T += V^T . P^T : A = V^T frag (8B from Vs), B = sacc directly
        #pragma unroll
        for (int j = 0; j < 8; j++) {
            pk4 pf;
            pf.h = bf16x4{(bf16)sacc[j][0], (bf16)sacc[j][1],
                          (bf16)sacc[j][2], (bf16)sacc[j][3]};
            #pragma unroll
            for (int fb = 0; fb < 4; fb++) {
                pk4 vf;
                *(unsigned long long*)vf.d =
                    *(const unsigned long long*)&Vs[fb*16 + lr][j*16 + quad*4];
                o_accT[fb] = MFMA16(vf.s, pf.s, o_accT[fb]);
            }
        }
#else
        // Fallback: build K=32 B-frags of P^T via shuffles, MFMA32 with A=V^T.
        unsigned int p0[8], p1[8];
        #pragma unroll
        for (int j = 0; j < 8; j++) {
            pk4 pf;
            pf.h = bf16x4{(bf16)sacc[j][0], (bf16)sacc[j][1],
                          (bf16)sacc[j][2], (bf16)sacc[j][3]};
            p0[j] = pf.d[0]; p1[j] = pf.d[1];
        }
        const int srcA = lr + 16 * ((2 * quad) & 3);
        const int srcB = lr + 16 * ((2 * quad + 1) & 3);
        const bool hi = (quad >> 1) != 0;
        #pragma unroll
        for (int c = 0; c < 4; c++) {
            unsigned int a0 = __shfl(p0[2*c], srcA), a1 = __shfl(p0[2*c+1], srcA);
            unsigned int b0 = __shfl(p1[2*c], srcA), b1 = __shfl(p1[2*c+1], srcA);
            unsigned int c0 = __shfl(p0[2*c], srcB), c1 = __shfl(p0[2*c+1], srcB);
            unsigned int d0 = __shfl(p1[2*c], srcB), d1 = __shfl(p1[2*c+1], srcB);
            unsigned int fr[4];
            fr[0] = hi ? a1 : a0;
            fr[1] = hi ? b1 : b0;
            fr[2] = hi ? c1 : c0;
            fr[3] = hi ? d1 : d0;
            bf16x8 pf8 = *(bf16x8*)fr;
            #pragma unroll
            for (int fb = 0; fb < 4; fb++) {
                bf16x8 vf8 = *(const bf16x8*)&Vs[fb*16 + lr][c*32 + quad*8];
                o_accT[fb] = MFMA32(vf8, pf8, o_accT[fb]);
            }
        }
#endif
    }

    // epilogue: per-lane divide, store O^T -> o_ws[b,s,d] as bf16x4 runs
    const float inv = 1.0f / l_i;
    const int s = qt*64 + wave*16 + lr;
    #pragma unroll
    for (int fb = 0; fb < 4; fb++) {
        bf16x4 ov = {(bf16)(o_accT[fb][0] * inv), (bf16)(o_accT[fb][1] * inv),
                     (bf16)(o_accT[fb][2] * inv), (bf16)(o_accT[fb][3] * inv)};
        *(bf16x4*)(o_ws + ((size_t)b_ * 2048 + s) * 1024 + h*64 + fb*16 + quad*4) = ov;
    }
}

// ---------------------------------------------------------------------------
// Kernel 3: output projection.  out[m,n] = o[m,:] . Wo[n,:] + bo[n], fp32 out
// ---------------------------------------------------------------------------
__global__ __launch_bounds__(256)
void out_gemm(const bf16* __restrict__ o_ws,
              const bf16* __restrict__ wob, const float* __restrict__ bo,
              float* __restrict__ out)
{
    __shared__ bf16 As[128][32];
    __shared__ bf16 Bs[128][32];

    const int m0 = blockIdx.x * 128;
    const int n0 = blockIdx.y * 128;
    const int t    = threadIdx.x;
    const int wave = t >> 6;
    const int lane = t & 63;
    const int lr   = lane & 15;
    const int quad = lane >> 4;
    const int wm = (wave & 1) * 64;
    const int wn = (wave >> 1) * 64;

    const int srow = wave * 32 + (lane >> 2);
    const int scol = (lane & 3) * 8;
    const bf16* ga0 = o_ws + (size_t)(m0 + srow) * 1024 + scol;
    const bf16* ga1 = o_ws + (size_t)(m0 + srow + 16) * 1024 + scol;
    const bf16* gb0 = wob  + (size_t)(n0 + srow) * 1024 + scol;
    const bf16* gb1 = wob  + (size_t)(n0 + srow + 16) * 1024 + scol;
    bf16* la0 = &As[srow][scol];
    bf16* la1 = &As[srow + 16][scol];
    bf16* lb0 = &Bs[srow][scol];
    bf16* lb1 = &Bs[srow + 16][scol];

    f32x4 acc[4][4] = {};

    for (int k0 = 0; k0 < 1024; k0 += 32) {
        GLL(ga0 + k0, la0);
        GLL(ga1 + k0, la1);
        GLL(gb0 + k0, lb0);
        GLL(gb1 + k0, lb1);
        __syncthreads();

        bf16x8 af[4], bfr[4];
        #pragma unroll
        for (int i = 0; i < 4; i++) af[i]  = *(const bf16x8*)&As[wm + i*16 + lr][quad*8];
        #pragma unroll
        for (int j = 0; j < 4; j++) bfr[j] = *(const bf16x8*)&Bs[wn + j*16 + lr][quad*8];
        #pragma unroll
        for (int i = 0; i < 4; i++)
            #pragma unroll
            for (int j = 0; j < 4; j++)
                acc[i][j] = MFMA32(af[i], bfr[j], acc[i][j]);
        __syncthreads();
    }

    #pragma unroll
    for (int j = 0; j < 4; j++) {
        const int col = n0 + wn + j * 16 + lr;
        const float bb = bo[col];
        #pragma unroll
        for (int i = 0; i < 4; i++)
            #pragma unroll
            for (int r = 0; r < 4; r++) {
                const int row = m0 + wm + i * 16 + quad * 4 + r;
                out[(size_t)row * 1024 + col] = acc[i][j][r] + bb;
            }
    }
}

extern "C" void kernel_launch(void* const* d_in, const int* in_sizes, int n_in,
                              void* d_out, int out_size, void* d_ws, size_t ws_size,
                              hipStream_t stream) {
    (void)in_sizes; (void)n_in; (void)out_size; (void)ws_size;
    const float* x  = (const float*)d_in[0];
    const float* Wq = (const float*)d_in[1];
    const float* bq = (const float*)d_in[2];
    const float* Wk = (const float*)d_in[3];
    const float* bk = (const float*)d_in[4];
    const float* Wv = (const float*)d_in[5];
    const float* bv = (const float*)d_in[6];
    const float* Wo = (const float*)d_in[7];
    const float* bo = (const float*)d_in[8];
    float* out = (float*)d_out;

    char* ws = (char*)d_ws;
    const size_t MB = 1024 * 1024;
    bf16* xb   = (bf16*)(ws);
    bf16* wqb  = (bf16*)(ws + 8 * MB);
    bf16* wkb  = (bf16*)(ws + 10 * MB);
    bf16* wvb  = (bf16*)(ws + 12 * MB);
    bf16* wob  = (bf16*)(ws + 14 * MB);
    bf16* q_ws = (bf16*)(ws + 16 * MB);
    bf16* k_ws = (bf16*)(ws + 24 * MB);
    bf16* v_ws = (bf16*)(ws + 32 * MB);
    bf16* o_ws = (bf16*)(ws + 40 * MB);

    hipLaunchKernelGGL(cvt_bf16, dim3(8192), dim3(256), 0, stream,
                       x, Wq, Wk, Wv, Wo, xb, wqb, wkb, wvb, wob);
    hipLaunchKernelGGL(qkv_gemm, dim3(32, 8, 3), dim3(256), 0, stream,
                       xb, wqb, bq, wkb, bk, wvb, bv, q_ws, k_ws, v_ws);
    hipLaunchKernelGGL(attn, dim3(32, 32), dim3(256), 0, stream,
                       q_ws, k_ws, v_ws, o_ws);
    hipLaunchKernelGGL(out_gemm, dim3(32, 8), dim3(256), 0, stream,
                       o_ws, wob, bo, out);
}

// Round 5
// 240.087 us; speedup vs baseline: 1.3180x; 1.0154x over previous
//
#include <hip/hip_runtime.h>

// MHA: B=2 S=2048 D=1024 H=16 DH=64.  All GEMMs bf16 MFMA, fp32 acc.
// R5: (a) qkv q/k epilogues transposed through LDS -> coalesced bf16x8 stores
//     (was 64 scalar 2B stores/thread). (b) out_gemm 64x128 tiles (2 blk/CU)
//     + LDS-transpose epilogue -> float4 stores. (c) attn: K/V prefetch into
//     VGPRs overlaps global latency with compute; o_ws epilogue coalesced
//     through reused Ks LDS.
// ws: xb 8MB @0 | wq/wk/wv/wo bf16 2MB each @8/10/12/14MB | q 8MB @16MB |
//     k 8MB @24MB | v^T 8MB @32MB [b,h,dh,s] | o 8MB @40MB  (needs 48MB ws)

typedef __bf16 bf16;
typedef bf16 bf16x8 __attribute__((ext_vector_type(8)));
typedef bf16 bf16x4 __attribute__((ext_vector_type(4)));
typedef short s16x4 __attribute__((ext_vector_type(4)));
typedef float f32x4 __attribute__((ext_vector_type(4)));

#define MFMA32(a, b, c) __builtin_amdgcn_mfma_f32_16x16x32_bf16(a, b, c, 0, 0, 0)

#if __has_builtin(__builtin_amdgcn_mfma_f32_16x16x16bf16_1k)
#define HAVE_MFMA16 1
#define MFMA16(a, b, c) __builtin_amdgcn_mfma_f32_16x16x16bf16_1k(a, b, c, 0, 0, 0)
#else
#define HAVE_MFMA16 0
#endif

// async global->LDS, 16B per lane; LDS dst must be wave-uniform base + lane*16
#define GLL(g, l) __builtin_amdgcn_global_load_lds(                              \
    (const __attribute__((address_space(1))) void*)(const void*)(g),             \
    (__attribute__((address_space(3))) void*)(void*)(l), 16, 0, 0)

union pk4 { bf16x4 h; s16x4 s; unsigned int d[2]; };

// ---------------------------------------------------------------------------
// Kernel 0: fp32 -> bf16 conversion of x and the four weight matrices.
// ---------------------------------------------------------------------------
__global__ __launch_bounds__(256)
void cvt_bf16(const float* __restrict__ x,  const float* __restrict__ Wq,
              const float* __restrict__ Wk, const float* __restrict__ Wv,
              const float* __restrict__ Wo,
              bf16* __restrict__ xb, bf16* __restrict__ wqb, bf16* __restrict__ wkb,
              bf16* __restrict__ wvb, bf16* __restrict__ wob)
{
    const int idx = blockIdx.x * 256 + threadIdx.x;   // float4 index
    const float* src; bf16* dst; int off;
    if (idx < 1048576) { src = x; dst = xb; off = idx; }
    else {
        const int r = idx - 1048576;
        const int seg = r >> 18;          // 0..3  (262144 float4 per W)
        off = r & 262143;
        src = (seg == 0) ? Wq : (seg == 1) ? Wk : (seg == 2) ? Wv : Wo;
        dst = (seg == 0) ? wqb : (seg == 1) ? wkb : (seg == 2) ? wvb : wob;
    }
    const float4 v = ((const float4*)src)[off];
    bf16x4 o = {(bf16)v.x, (bf16)v.y, (bf16)v.z, (bf16)v.w};
    *(bf16x4*)(dst + (size_t)off * 4) = o;
}

// ---------------------------------------------------------------------------
// Kernel 1: fused QKV projection.  grid (32 Mtiles, 8 Ntiles, 3), 256 thr.
// m97-style GLL staging; ALL epilogues LDS-transposed -> coalesced stores.
// ---------------------------------------------------------------------------
__global__ __launch_bounds__(256)
void qkv_gemm(const bf16* __restrict__ xb,
              const bf16* __restrict__ wqb, const float* __restrict__ bq,
              const bf16* __restrict__ wkb, const float* __restrict__ bk,
              const bf16* __restrict__ wvb, const float* __restrict__ bv,
              bf16* __restrict__ q_ws, bf16* __restrict__ k_ws, bf16* __restrict__ v_ws)
{
    const int z = blockIdx.z;
    const bf16*  W    = (z == 0) ? wqb : (z == 1) ? wkb : wvb;
    const float* bias = (z == 0) ? bq  : (z == 1) ? bk  : bv;

    __shared__ bf16 As[128][32];   // unpadded: required by global_load_lds layout
    __shared__ bf16 Bs[128][32];
    __shared__ char ebuf[17408];   // epilogue: Et[128][68] bf16 OR Vt[64][132] bf16
    bf16 (*Et)[68]  = (bf16(*)[68])ebuf;
    bf16 (*Vt)[132] = (bf16(*)[132])ebuf;

    const int m0 = blockIdx.x * 128;
    const int n0 = blockIdx.y * 128;
    const int t    = threadIdx.x;
    const int wave = t >> 6;
    const int lane = t & 63;
    const int lr   = lane & 15;
    const int quad = lane >> 4;
    const int wm = (wave & 1) * 64;
    const int wn = (wave >> 1) * 64;

    const int srow = wave * 32 + (lane >> 2);
    const int scol = (lane & 3) * 8;
    const bf16* ga0 = xb + (size_t)(m0 + srow) * 1024 + scol;
    const bf16* ga1 = xb + (size_t)(m0 + srow + 16) * 1024 + scol;
    const bf16* gb0 = W  + (size_t)(n0 + srow) * 1024 + scol;
    const bf16* gb1 = W  + (size_t)(n0 + srow + 16) * 1024 + scol;
    bf16* la0 = &As[srow][scol];
    bf16* la1 = &As[srow + 16][scol];
    bf16* lb0 = &Bs[srow][scol];
    bf16* lb1 = &Bs[srow + 16][scol];

    f32x4 acc[4][4] = {};

    for (int k0 = 0; k0 < 1024; k0 += 32) {
        GLL(ga0 + k0, la0);
        GLL(ga1 + k0, la1);
        GLL(gb0 + k0, lb0);
        GLL(gb1 + k0, lb1);
        __syncthreads();

        bf16x8 af[4], bfr[4];
        #pragma unroll
        for (int i = 0; i < 4; i++) af[i]  = *(const bf16x8*)&As[wm + i*16 + lr][quad*8];
        #pragma unroll
        for (int j = 0; j < 4; j++) bfr[j] = *(const bf16x8*)&Bs[wn + j*16 + lr][quad*8];
        #pragma unroll
        for (int i = 0; i < 4; i++)
            #pragma unroll
            for (int j = 0; j < 4; j++)
                acc[i][j] = MFMA32(af[i], bfr[j], acc[i][j]);
        __syncthreads();
    }

    const int bi = m0 >> 11, si0 = m0 & 2047;
    if (z < 2) {
        // q (pre-scaled 0.125) / k -> [b,h,s,dh]: per head the 128si x 64dh
        // block is 16KB contiguous -> transpose via LDS, coalesced bf16x8.
        bf16* hw = (z == 0) ? q_ws : k_ws;
        const float sc = (z == 0) ? 0.125f : 1.0f;
        #pragma unroll
        for (int ph = 0; ph < 2; ph++) {
            if ((wave >> 1) == ph) {
                #pragma unroll
                for (int j = 0; j < 4; j++) {
                    const float bb = bias[n0 + ph * 64 + j * 16 + lr];
                    #pragma unroll
                    for (int i = 0; i < 4; i++)
                        #pragma unroll
                        for (int r = 0; r < 4; r++)
                            Et[wm + i*16 + quad*4 + r][j*16 + lr] =
                                (bf16)((acc[i][j][r] + bb) * sc);
                }
            }
            __syncthreads();
            const int hh = (n0 >> 6) + ph;
            bf16* dst = hw + (((size_t)bi * 16 + hh) * 2048 + si0) * 64;
            const int row = t >> 1, cc = (t & 1) * 32;
            #pragma unroll
            for (int e = 0; e < 4; e++)
                *(bf16x8*)(dst + (size_t)row * 64 + cc + e * 8) =
                    *(const bf16x8*)&Et[row][cc + e * 8];
            __syncthreads();
        }
    } else {
        // v -> [b,h,dh,s] (transposed): stage feature-major, coalesced stores
        #pragma unroll
        for (int ph = 0; ph < 2; ph++) {
            if ((wave >> 1) == ph) {
                #pragma unroll
                for (int j = 0; j < 4; j++) {
                    const float bb = bias[n0 + ph * 64 + j * 16 + lr];
                    #pragma unroll
                    for (int i = 0; i < 4; i++)
                        #pragma unroll
                        for (int r = 0; r < 4; r++)
                            Vt[j * 16 + lr][wm + i * 16 + quad * 4 + r] =
                                (bf16)(acc[i][j][r] + bb);
                }
            }
            __syncthreads();
            const int c  = t >> 2;             // local feature 0..63
            const int sc_ = (t & 3) * 32;
            const int col = n0 + ph * 64 + c;
            const int h = col >> 6, dh = col & 63;
            bf16* dst = v_ws + (((size_t)bi * 16 + h) * 64 + dh) * 2048 + si0 + sc_;
            #pragma unroll
            for (int e = 0; e < 4; e++)
                *(bf16x8*)(dst + e * 8) = *(const bf16x8*)&Vt[c][sc_ + e * 8];
            __syncthreads();
        }
    }
}

// ---------------------------------------------------------------------------
// Kernel 2: flash attention, fully transposed.  grid (32 q-tiles, 32 b*h).
// S^T = K.Q^T; softmaxed sacc is directly the B-operand of PV (O^T = V^T.P^T);
// per-row stats stay per-lane.  K/V prefetched into VGPRs one tile ahead.
// LDS: Ks 18KB + Vs 17KB = 35KB -> 4 blocks/CU.
// ---------------------------------------------------------------------------
__global__ __launch_bounds__(256, 4)
void attn(const bf16* __restrict__ q_ws, const bf16* __restrict__ k_ws,
          const bf16* __restrict__ v_ws, bf16* __restrict__ o_ws)
{
    const int qt = blockIdx.x;
    const int bh = blockIdx.y;           // b*16+h
    const int b_ = bh >> 4, h = bh & 15;

    const bf16* qbase = q_ws + (size_t)bh * 2048 * 64;
    const bf16* kbase = k_ws + (size_t)bh * 2048 * 64;
    const bf16* vbase = v_ws + (size_t)bh * 64 * 2048;  // [64][2048] V^T

    __shared__ bf16 Ks[128][72];     // [key][feat]
    __shared__ bf16 Vs[64][136];     // [feat][key]

    const int t    = threadIdx.x;
    const int wave = t >> 6;
    const int lane = t & 63;
    const int lr   = lane & 15;
    const int quad = lane >> 4;

    // Q fragments (pre-scaled by 0.125): B-operand of QK^T, n=qrow=lr
    bf16x8 aq[2];
    #pragma unroll
    for (int kc = 0; kc < 2; kc++)
        aq[kc] = *(const bf16x8*)(qbase +
            (size_t)(qt*64 + wave*16 + lr) * 64 + kc*32 + quad*8);

    float m_i = -1e30f, l_i = 0.f;       // stats for qrow = lr (per-lane)
    f32x4 o_accT[4] = {};                // O^T: rows feat, cols qrow=lr
    const float C = 1.44269504f;         // log2(e)

    // prefetch tile 0 into registers
    bf16x8 kreg[4], vreg[4];
    #pragma unroll
    for (int u = 0; u < 4; u++) {
        const int c = t + u * 256;
        kreg[u] = *(const bf16x8*)(kbase + (size_t)c * 8);
        vreg[u] = *(const bf16x8*)(vbase + (size_t)(c >> 4) * 2048 + (c & 15) * 8);
    }

    for (int kt = 0; kt < 16; kt++) {
        __syncthreads();     // previous tile's LDS reads done
        #pragma unroll
        for (int u = 0; u < 4; u++) {
            const int c = t + u * 256;
            *(bf16x8*)&Ks[c >> 3][(c & 7) * 8] = kreg[u];
            *(bf16x8*)&Vs[c >> 4][(c & 15) * 8] = vreg[u];
        }
        __syncthreads();
        // issue next tile's loads now; latency hides under compute below
        if (kt < 15) {
            #pragma unroll
            for (int u = 0; u < 4; u++) {
                const int c = t + u * 256;
                kreg[u] = *(const bf16x8*)(kbase + (size_t)(kt+1) * 8192 + c * 8);
                vreg[u] = *(const bf16x8*)(vbase + (size_t)(c >> 4) * 2048
                                           + (kt+1) * 128 + (c & 15) * 8);
            }
        }

        // S^T: 8 key-frags x 16 qrows
        f32x4 sacc[8];
        #pragma unroll
        for (int j = 0; j < 8; j++) {
            bf16x8 kf0 = *(const bf16x8*)&Ks[j*16 + lr][quad*8];
            bf16x8 kf1 = *(const bf16x8*)&Ks[j*16 + lr][32 + quad*8];
            f32x4 a = {0.f, 0.f, 0.f, 0.f};
            a = MFMA32(kf0, aq[0], a);
            a = MFMA32(kf1, aq[1], a);
            sacc[j] = a;
        }

        // online softmax for qrow = lr (lane holds 32 of 128 keys)
        float m = -1e30f;
        #pragma unroll
        for (int j = 0; j < 8; j++)
            #pragma unroll
            for (int r = 0; r < 4; r++) m = fmaxf(m, sacc[j][r]);
        m = fmaxf(m, __shfl_xor(m, 16));
        m = fmaxf(m, __shfl_xor(m, 32));
        const float nm = fmaxf(m_i, m);
        const float al = exp2f((m_i - nm) * C);
        m_i = nm;
        const float nmc = nm * C;
        float rs = 0.f;
        #pragma unroll
        for (int j = 0; j < 8; j++)
            #pragma unroll
            for (int r = 0; r < 4; r++) {
                const float p = exp2f(fmaf(sacc[j][r], C, -nmc));
                sacc[j][r] = p;
                rs += p;
            }
        // rescale O^T: alpha is a per-lane scalar (cols are qrow=lr)
        #pragma unroll
        for (int n = 0; n < 4; n++)
            #pragma unroll
            for (int r = 0; r < 4; r++) o_accT[n][r] *= al;
        rs += __shfl_xor(rs, 16);
        rs += __shfl_xor(rs, 32);
        l_i = l_i * al + rs;

#if HAVE_MFMA16
        // O^T += V^T . P^T : A = V^T frag (8B from Vs), B = sacc directly
        #pragma unroll
        for (int j = 0; j < 8; j++) {
            pk4 pf;
            pf.h = bf16x4{(bf16)sacc[j][0], (bf16)sacc[j][1],
                          (bf16)sacc[j][2], (bf16)sacc[j][3]};
            #pragma unroll
            for (int fb = 0; fb < 4; fb++) {
                pk4 vf;
                *(unsigned long long*)vf.d =
                    *(const unsigned long long*)&Vs[fb*16 + lr][j*16 + quad*4];
                o_accT[fb] = MFMA16(vf.s, pf.s, o_accT[fb]);
            }
        }
#else
        // Fallback: build K=32 B-frags of P^T via shuffles, MFMA32 with A=V^T.
        unsigned int p0[8], p1[8];
        #pragma unroll
        for (int j = 0; j < 8; j++) {
            pk4 pf;
            pf.h = bf16x4{(bf16)sacc[j][0], (bf16)sacc[j][1],
                          (bf16)sacc[j][2], (bf16)sacc[j][3]};
            p0[j] = pf.d[0]; p1[j] = pf.d[1];
        }
        const int srcA = lr + 16 * ((2 * quad) & 3);
        const int srcB = lr + 16 * ((2 * quad + 1) & 3);
        const bool hi = (quad >> 1) != 0;
        #pragma unroll
        for (int c = 0; c < 4; c++) {
            unsigned int a0 = __shfl(p0[2*c], srcA), a1 = __shfl(p0[2*c+1], srcA);
            unsigned int b0 = __shfl(p1[2*c], srcA), b1 = __shfl(p1[2*c+1], srcA);
            unsigned int c0 = __shfl(p0[2*c], srcB), c1 = __shfl(p0[2*c+1], srcB);
            unsigned int d0 = __shfl(p1[2*c], srcB), d1 = __shfl(p1[2*c+1], srcB);
            unsigned int fr[4];
            fr[0] = hi ? a1 : a0;
            fr[1] = hi ? b1 : b0;
            fr[2] = hi ? c1 : c0;
            fr[3] = hi ? d1 : d0;
            bf16x8 pf8 = *(bf16x8*)fr;
            #pragma unroll
            for (int fb = 0; fb < 4; fb++) {
                bf16x8 vf8 = *(const bf16x8*)&Vs[fb*16 + lr][c*32 + quad*8];
                o_accT[fb] = MFMA32(vf8, pf8, o_accT[fb]);
            }
        }
#endif
    }

    // epilogue: divide, transpose through reused Ks LDS, coalesced stores
    __syncthreads();                      // all waves done reading Ks/Vs
    bf16 (*OsE)[68] = (bf16(*)[68])&Ks[0][0];    // 64 x 68 bf16 = 8.7KB
    const float inv = 1.0f / l_i;
    const int sil = wave * 16 + lr;       // local si 0..63
    #pragma unroll
    for (int fb = 0; fb < 4; fb++)
        #pragma unroll
        for (int r = 0; r < 4; r++)
            OsE[sil][fb*16 + quad*4 + r] = (bf16)(o_accT[fb][r] * inv);
    __syncthreads();
    const int row = t >> 2, seg = (t & 3) * 16;
    bf16* dst = o_ws + ((size_t)b_ * 2048 + qt*64 + row) * 1024 + h*64 + seg;
    *(bf16x8*)(dst)     = *(const bf16x8*)&OsE[row][seg];
    *(bf16x8*)(dst + 8) = *(const bf16x8*)&OsE[row][seg + 8];
}

// ---------------------------------------------------------------------------
// Kernel 3: output projection.  64x128 tiles, grid (64,8) = 512 blocks.
// out[m,n] = o[m,:] . Wo[n,:] + bo[n], fp32 out via LDS-transposed epilogue.
// ---------------------------------------------------------------------------
__global__ __launch_bounds__(256)
void out_gemm(const bf16* __restrict__ o_ws,
              const bf16* __restrict__ wob, const float* __restrict__ bo,
              float* __restrict__ out)
{
    __shared__ bf16 As[64][32];
    __shared__ bf16 Bs[128][32];
    __shared__ float Ot[64][68];   // 17.4KB epilogue staging

    const int m0 = blockIdx.x * 64;
    const int n0 = blockIdx.y * 128;
    const int t    = threadIdx.x;
    const int wave = t >> 6;
    const int lane = t & 63;
    const int lr   = lane & 15;
    const int quad = lane >> 4;
    const int wm = (wave & 1) * 32;
    const int wn = (wave >> 1) * 64;

    const int srowA = wave * 16 + (lane >> 2);   // 0..63
    const int srowB = wave * 32 + (lane >> 2);
    const int scol  = (lane & 3) * 8;
    const bf16* gaA = o_ws + (size_t)(m0 + srowA) * 1024 + scol;
    const bf16* gb0 = wob  + (size_t)(n0 + srowB) * 1024 + scol;
    const bf16* gb1 = wob  + (size_t)(n0 + srowB + 16) * 1024 + scol;
    bf16* laA = &As[srowA][scol];
    bf16* lb0 = &Bs[srowB][scol];
    bf16* lb1 = &Bs[srowB + 16][scol];

    f32x4 acc[2][4] = {};

    for (int k0 = 0; k0 < 1024; k0 += 32) {
        GLL(gaA + k0, laA);
        GLL(gb0 + k0, lb0);
        GLL(gb1 + k0, lb1);
        __syncthreads();

        bf16x8 af[2], bfr[4];
        #pragma unroll
        for (int i = 0; i < 2; i++) af[i]  = *(const bf16x8*)&As[wm + i*16 + lr][quad*8];
        #pragma unroll
        for (int j = 0; j < 4; j++) bfr[j] = *(const bf16x8*)&Bs[wn + j*16 + lr][quad*8];
        #pragma unroll
        for (int i = 0; i < 2; i++)
            #pragma unroll
            for (int j = 0; j < 4; j++)
                acc[i][j] = MFMA32(af[i], bfr[j], acc[i][j]);
        __syncthreads();
    }

    #pragma unroll
    for (int ph = 0; ph < 2; ph++) {
        if ((wave >> 1) == ph) {
            #pragma unroll
            for (int j = 0; j < 4; j++) {
                const float bb = bo[n0 + ph * 64 + j * 16 + lr];
                #pragma unroll
                for (int i = 0; i < 2; i++)
                    #pragma unroll
                    for (int r = 0; r < 4; r++)
                        Ot[wm + i*16 + quad*4 + r][j*16 + lr] = acc[i][j][r] + bb;
            }
        }
        __syncthreads();
        const int row = t >> 2, seg = (t & 3) * 16;
        float* dst = out + (size_t)(m0 + row) * 1024 + n0 + ph * 64 + seg;
        #pragma unroll
        for (int e = 0; e < 4; e++)
            *(float4*)(dst + e * 4) = *(const float4*)&Ot[row][seg + e * 4];
        __syncthreads();
    }
}

extern "C" void kernel_launch(void* const* d_in, const int* in_sizes, int n_in,
                              void* d_out, int out_size, void* d_ws, size_t ws_size,
                              hipStream_t stream) {
    (void)in_sizes; (void)n_in; (void)out_size; (void)ws_size;
    const float* x  = (const float*)d_in[0];
    const float* Wq = (const float*)d_in[1];
    const float* bq = (const float*)d_in[2];
    const float* Wk = (const float*)d_in[3];
    const float* bk = (const float*)d_in[4];
    const float* Wv = (const float*)d_in[5];
    const float* bv = (const float*)d_in[6];
    const float* Wo = (const float*)d_in[7];
    const float* bo = (const float*)d_in[8];
    float* out = (float*)d_out;

    char* ws = (char*)d_ws;
    const size_t MB = 1024 * 1024;
    bf16* xb   = (bf16*)(ws);
    bf16* wqb  = (bf16*)(ws + 8 * MB);
    bf16* wkb  = (bf16*)(ws + 10 * MB);
    bf16* wvb  = (bf16*)(ws + 12 * MB);
    bf16* wob  = (bf16*)(ws + 14 * MB);
    bf16* q_ws = (bf16*)(ws + 16 * MB);
    bf16* k_ws = (bf16*)(ws + 24 * MB);
    bf16* v_ws = (bf16*)(ws + 32 * MB);
    bf16* o_ws = (bf16*)(ws + 40 * MB);

    hipLaunchKernelGGL(cvt_bf16, dim3(8192), dim3(256), 0, stream,
                       x, Wq, Wk, Wv, Wo, xb, wqb, wkb, wvb, wob);
    hipLaunchKernelGGL(qkv_gemm, dim3(32, 8, 3), dim3(256), 0, stream,
                       xb, wqb, bq, wkb, bk, wvb, bv, q_ws, k_ws, v_ws);
    hipLaunchKernelGGL(attn, dim3(32, 32), dim3(256), 0, stream,
                       q_ws, k_ws, v_ws, o_ws);
    hipLaunchKernelGGL(out_gemm, dim3(64, 8), dim3(256), 0, stream,
                       o_ws, wob, bo, out);
}

// Round 6
// 230.251 us; speedup vs baseline: 1.3743x; 1.0427x over previous
//
#include <hip/hip_runtime.h>

// MHA: B=2 S=2048 D=1024 H=16 DH=64.  All GEMMs bf16 MFMA, fp32 acc.
// R6: (a) GEMMs: BK=64 K-loop (half the barriers) + XOR column swizzle so
//     fragment ds_read_b128 is 2-way conflict-free with GLL's forced layout.
//     (b) attn: row-sum l via ones-MFMA on the idle MFMA pipe (-32 VALU/tile),
//     Vs column-permuted so V-frags are 16x b128 (was 32x b64), fused
//     exp->pack->PV loop.
// ws: xb 8MB @0 | wq/wk/wv/wo bf16 2MB each @8/10/12/14MB | q 8MB @16MB |
//     k 8MB @24MB | v^T 8MB @32MB [b,h,dh,s] | o 8MB @40MB  (needs 48MB ws)

typedef __bf16 bf16;
typedef bf16 bf16x8 __attribute__((ext_vector_type(8)));
typedef bf16 bf16x4 __attribute__((ext_vector_type(4)));
typedef short s16x4 __attribute__((ext_vector_type(4)));
typedef float f32x4 __attribute__((ext_vector_type(4)));

#define MFMA32(a, b, c) __builtin_amdgcn_mfma_f32_16x16x32_bf16(a, b, c, 0, 0, 0)

#if __has_builtin(__builtin_amdgcn_mfma_f32_16x16x16bf16_1k)
#define HAVE_MFMA16 1
#define MFMA16(a, b, c) __builtin_amdgcn_mfma_f32_16x16x16bf16_1k(a, b, c, 0, 0, 0)
#else
#define HAVE_MFMA16 0
#endif

// async global->LDS, 16B per lane; LDS dst must be wave-uniform base + lane*16
#define GLL(g, l) __builtin_amdgcn_global_load_lds(                              \
    (const __attribute__((address_space(1))) void*)(const void*)(g),             \
    (__attribute__((address_space(3))) void*)(void*)(l), 16, 0, 0)

union pk4 { bf16x4 h; s16x4 s; unsigned int d[2]; };
union v8u { bf16x8 v; bf16x4 h[2]; s16x4 s[2]; };

// ---------------------------------------------------------------------------
// Kernel 0: fp32 -> bf16 conversion of x and the four weight matrices.
// ---------------------------------------------------------------------------
__global__ __launch_bounds__(256)
void cvt_bf16(const float* __restrict__ x,  const float* __restrict__ Wq,
              const float* __restrict__ Wk, const float* __restrict__ Wv,
              const float* __restrict__ Wo,
              bf16* __restrict__ xb, bf16* __restrict__ wqb, bf16* __restrict__ wkb,
              bf16* __restrict__ wvb, bf16* __restrict__ wob)
{
    const int idx = blockIdx.x * 256 + threadIdx.x;   // float4 index
    const float* src; bf16* dst; int off;
    if (idx < 1048576) { src = x; dst = xb; off = idx; }
    else {
        const int r = idx - 1048576;
        const int seg = r >> 18;          // 0..3  (262144 float4 per W)
        off = r & 262143;
        src = (seg == 0) ? Wq : (seg == 1) ? Wk : (seg == 2) ? Wv : Wo;
        dst = (seg == 0) ? wqb : (seg == 1) ? wkb : (seg == 2) ? wvb : wob;
    }
    const float4 v = ((const float4*)src)[off];
    bf16x4 o = {(bf16)v.x, (bf16)v.y, (bf16)v.z, (bf16)v.w};
    *(bf16x4*)(dst + (size_t)off * 4) = o;
}

// ---------------------------------------------------------------------------
// Kernel 1: fused QKV projection.  grid (32 Mtiles, 8 Ntiles, 3), 256 thr.
// BK=64, GLL staging with XOR swizzle: phys col p of row R holds
// k = p ^ ((R&7)*8)  ->  frag reads 2-way conflict-free.
// ---------------------------------------------------------------------------
__global__ __launch_bounds__(256, 3)
void qkv_gemm(const bf16* __restrict__ xb,
              const bf16* __restrict__ wqb, const float* __restrict__ bq,
              const bf16* __restrict__ wkb, const float* __restrict__ bk,
              const bf16* __restrict__ wvb, const float* __restrict__ bv,
              bf16* __restrict__ q_ws, bf16* __restrict__ k_ws, bf16* __restrict__ v_ws)
{
    const int z = blockIdx.z;
    const bf16*  W    = (z == 0) ? wqb : (z == 1) ? wkb : wvb;
    const float* bias = (z == 0) ? bq  : (z == 1) ? bk  : bv;

    __shared__ bf16 As[128][64];   // unpadded (GLL); swizzled columns
    __shared__ bf16 Bs[128][64];
    __shared__ char ebuf[17408];   // epilogue: Et[128][68] bf16 OR Vt[64][132] bf16
    bf16 (*Et)[68]  = (bf16(*)[68])ebuf;
    bf16 (*Vt)[132] = (bf16(*)[132])ebuf;

    const int m0 = blockIdx.x * 128;
    const int n0 = blockIdx.y * 128;
    const int t    = threadIdx.x;
    const int wave = t >> 6;
    const int lane = t & 63;
    const int lr   = lane & 15;
    const int quad = lane >> 4;
    const int wm = (wave & 1) * 64;
    const int wn = (wave >> 1) * 64;

    // staging: wave stages rows [32w,32w+32), u=0..3 -> 8 rows/instr.
    // lane -> row 32w+8u+(lane>>3); phys col (lane&7)*8 holds swizzled k.
    const int srow8 = lane >> 3;
    const int pcol  = (lane & 7) * 8;
    const int gcol  = ((lane & 7) ^ (lane >> 3)) * 8;   // swizzled global col
    const bf16* gaU[4]; const bf16* gbU[4]; bf16* laU[4]; bf16* lbU[4];
    #pragma unroll
    for (int u = 0; u < 4; u++) {
        const int row = wave * 32 + u * 8 + srow8;
        gaU[u] = xb + (size_t)(m0 + row) * 1024 + gcol;
        gbU[u] = W  + (size_t)(n0 + row) * 1024 + gcol;
        laU[u] = &As[row][pcol];
        lbU[u] = &Bs[row][pcol];
    }
    const int swA = (lr & 7) * 8;   // frag read swizzle for row wm+i*16+lr

    f32x4 acc[4][4] = {};

    for (int k0 = 0; k0 < 1024; k0 += 64) {
        #pragma unroll
        for (int u = 0; u < 4; u++) {
            GLL(gaU[u] + k0, laU[u]);
            GLL(gbU[u] + k0, lbU[u]);
        }
        __syncthreads();

        bf16x8 af[4][2], bfr[4][2];
        #pragma unroll
        for (int i = 0; i < 4; i++)
            #pragma unroll
            for (int kc = 0; kc < 2; kc++)
                af[i][kc] = *(const bf16x8*)&As[wm + i*16 + lr][(kc*32 + quad*8) ^ swA];
        #pragma unroll
        for (int j = 0; j < 4; j++)
            #pragma unroll
            for (int kc = 0; kc < 2; kc++)
                bfr[j][kc] = *(const bf16x8*)&Bs[wn + j*16 + lr][(kc*32 + quad*8) ^ swA];
        #pragma unroll
        for (int kc = 0; kc < 2; kc++)
            #pragma unroll
            for (int i = 0; i < 4; i++)
                #pragma unroll
                for (int j = 0; j < 4; j++)
                    acc[i][j] = MFMA32(af[i][kc], bfr[j][kc], acc[i][j]);
        __syncthreads();
    }

    const int bi = m0 >> 11, si0 = m0 & 2047;
    if (z < 2) {
        // q (pre-scaled 0.125) / k -> [b,h,s,dh] via LDS transpose
        bf16* hw = (z == 0) ? q_ws : k_ws;
        const float sc = (z == 0) ? 0.125f : 1.0f;
        #pragma unroll
        for (int ph = 0; ph < 2; ph++) {
            if ((wave >> 1) == ph) {
                #pragma unroll
                for (int j = 0; j < 4; j++) {
                    const float bb = bias[n0 + ph * 64 + j * 16 + lr];
                    #pragma unroll
                    for (int i = 0; i < 4; i++)
                        #pragma unroll
                        for (int r = 0; r < 4; r++)
                            Et[wm + i*16 + quad*4 + r][j*16 + lr] =
                                (bf16)((acc[i][j][r] + bb) * sc);
                }
            }
            __syncthreads();
            const int hh = (n0 >> 6) + ph;
            bf16* dst = hw + (((size_t)bi * 16 + hh) * 2048 + si0) * 64;
            const int row = t >> 1, cc = (t & 1) * 32;
            #pragma unroll
            for (int e = 0; e < 4; e++)
                *(bf16x8*)(dst + (size_t)row * 64 + cc + e * 8) =
                    *(const bf16x8*)&Et[row][cc + e * 8];
            __syncthreads();
        }
    } else {
        // v -> [b,h,dh,s] (transposed) via LDS
        #pragma unroll
        for (int ph = 0; ph < 2; ph++) {
            if ((wave >> 1) == ph) {
                #pragma unroll
                for (int j = 0; j < 4; j++) {
                    const float bb = bias[n0 + ph * 64 + j * 16 + lr];
                    #pragma unroll
                    for (int i = 0; i < 4; i++)
                        #pragma unroll
                        for (int r = 0; r < 4; r++)
                            Vt[j * 16 + lr][wm + i * 16 + quad * 4 + r] =
                                (bf16)(acc[i][j][r] + bb);
                }
            }
            __syncthreads();
            const int c  = t >> 2;             // local feature 0..63
            const int sc_ = (t & 3) * 32;
            const int col = n0 + ph * 64 + c;
            const int h = col >> 6, dh = col & 63;
            bf16* dst = v_ws + (((size_t)bi * 16 + h) * 64 + dh) * 2048 + si0 + sc_;
            #pragma unroll
            for (int e = 0; e < 4; e++)
                *(bf16x8*)(dst + e * 8) = *(const bf16x8*)&Vt[c][sc_ + e * 8];
            __syncthreads();
        }
    }
}

// ---------------------------------------------------------------------------
// Kernel 2: flash attention, fully transposed.  grid (32 q-tiles, 32 b*h).
// S^T = K.Q^T; softmaxed sacc is directly the B-operand of PV (O^T = V^T.P^T).
// l-sum via ones-MFMA; Vs column-permuted: phys col' = q*32 + j*4 + e for
// key = j*16 + q*4 + e  ->  V-frags are contiguous b128 reads.
// LDS: Ks 18KB + Vs 17KB = 35KB -> 4 blocks/CU.
// ---------------------------------------------------------------------------
__global__ __launch_bounds__(256, 4)
void attn(const bf16* __restrict__ q_ws, const bf16* __restrict__ k_ws,
          const bf16* __restrict__ v_ws, bf16* __restrict__ o_ws)
{
    const int qt = blockIdx.x;
    const int bh = blockIdx.y;           // b*16+h
    const int b_ = bh >> 4, h = bh & 15;

    const bf16* qbase = q_ws + (size_t)bh * 2048 * 64;
    const bf16* kbase = k_ws + (size_t)bh * 2048 * 64;
    const bf16* vbase = v_ws + (size_t)bh * 64 * 2048;  // [64][2048] V^T

    __shared__ bf16 Ks[128][72];     // [key][feat]
    __shared__ bf16 Vs[64][136];     // [feat][permuted key]

    const int t    = threadIdx.x;
    const int wave = t >> 6;
    const int lane = t & 63;
    const int lr   = lane & 15;
    const int quad = lane >> 4;

    // Q fragments (pre-scaled by 0.125): B-operand of QK^T, n=qrow=lr
    bf16x8 aq[2];
    #pragma unroll
    for (int kc = 0; kc < 2; kc++)
        aq[kc] = *(const bf16x8*)(qbase +
            (size_t)(qt*64 + wave*16 + lr) * 64 + kc*32 + quad*8);

    float m_i = -1e30f, l_i = 0.f;       // stats for qrow = lr (per-lane)
    f32x4 o_accT[4] = {};                // O^T: rows feat, cols qrow=lr
    const float C = 1.44269504f;         // log2(e)
    const s16x4 ones = {0x3F80, 0x3F80, 0x3F80, 0x3F80};  // bf16 1.0 x4

    // prefetch tile 0 into registers
    bf16x8 kreg[4], vreg[4];
    #pragma unroll
    for (int u = 0; u < 4; u++) {
        const int c = t + u * 256;
        kreg[u] = *(const bf16x8*)(kbase + (size_t)c * 8);
        vreg[u] = *(const bf16x8*)(vbase + (size_t)(c >> 4) * 2048 + (c & 15) * 8);
    }

    for (int kt = 0; kt < 16; kt++) {
        __syncthreads();     // previous tile's LDS reads done
        #pragma unroll
        for (int u = 0; u < 4; u++) {
            const int c = t + u * 256;
            *(bf16x8*)&Ks[c >> 3][(c & 7) * 8] = kreg[u];
#if HAVE_MFMA16
            const int d = c >> 4, k_ = c & 15;
            const int lo = (k_ & 1) * 64 + (k_ >> 1) * 4;  // permuted col'
            v8u vv; vv.v = vreg[u];
            *(bf16x4*)&Vs[d][lo]      = vv.h[0];
            *(bf16x4*)&Vs[d][lo + 32] = vv.h[1];
#else
            *(bf16x8*)&Vs[c >> 4][(c & 15) * 8] = vreg[u];
#endif
        }
        __syncthreads();
        if (kt < 15) {
            #pragma unroll
            for (int u = 0; u < 4; u++) {
                const int c = t + u * 256;
                kreg[u] = *(const bf16x8*)(kbase + (size_t)(kt+1) * 8192 + c * 8);
                vreg[u] = *(const bf16x8*)(vbase + (size_t)(c >> 4) * 2048
                                           + (kt+1) * 128 + (c & 15) * 8);
            }
        }

        // S^T: 8 key-frags x 16 qrows
        f32x4 sacc[8];
        #pragma unroll
        for (int j = 0; j < 8; j++) {
            bf16x8 kf0 = *(const bf16x8*)&Ks[j*16 + lr][quad*8];
            bf16x8 kf1 = *(const bf16x8*)&Ks[j*16 + lr][32 + quad*8];
            f32x4 a = {0.f, 0.f, 0.f, 0.f};
            a = MFMA32(kf0, aq[0], a);
            a = MFMA32(kf1, aq[1], a);
            sacc[j] = a;
        }

        // online softmax max for qrow = lr (lane holds 32 of 128 keys)
        float m = -1e30f;
        #pragma unroll
        for (int j = 0; j < 8; j++)
            #pragma unroll
            for (int r = 0; r < 4; r++) m = fmaxf(m, sacc[j][r]);
        m = fmaxf(m, __shfl_xor(m, 16));
        m = fmaxf(m, __shfl_xor(m, 32));
        const float nm = fmaxf(m_i, m);
        const float al = exp2f((m_i - nm) * C);
        m_i = nm;
        const float nmc = nm * C;
        // rescale O^T: alpha is a per-lane scalar (cols are qrow=lr)
        #pragma unroll
        for (int n = 0; n < 4; n++)
            #pragma unroll
            for (int r = 0; r < 4; r++) o_accT[n][r] *= al;

#if HAVE_MFMA16
        // fused exp -> pack -> PV; l-sum via ones-MFMA (lands at col=lr)
        f32x4 lacc = {0.f, 0.f, 0.f, 0.f};
        #pragma unroll
        for (int c4 = 0; c4 < 4; c4++) {
            v8u vf[4];
            #pragma unroll
            for (int fb = 0; fb < 4; fb++)
                vf[fb].v = *(const bf16x8*)&Vs[fb*16 + lr][quad*32 + c4*8];
            #pragma unroll
            for (int jj = 0; jj < 2; jj++) {
                const int j = c4*2 + jj;
                pk4 pf;
                pf.h = bf16x4{
                    (bf16)exp2f(fmaf(sacc[j][0], C, -nmc)),
                    (bf16)exp2f(fmaf(sacc[j][1], C, -nmc)),
                    (bf16)exp2f(fmaf(sacc[j][2], C, -nmc)),
                    (bf16)exp2f(fmaf(sacc[j][3], C, -nmc))};
                #pragma unroll
                for (int fb = 0; fb < 4; fb++)
                    o_accT[fb] = MFMA16(vf[fb].s[jj], pf.s, o_accT[fb]);
                lacc = MFMA16(ones, pf.s, lacc);
            }
        }
        l_i = l_i * al + lacc[0];
#else
        // Fallback: exp into sacc, rs adds + shuffles, shuffle-built PV frags
        float rs = 0.f;
        #pragma unroll
        for (int j = 0; j < 8; j++)
            #pragma unroll
            for (int r = 0; r < 4; r++) {
                const float p = exp2f(fmaf(sacc[j][r], C, -nmc));
                sacc[j][r] = p;
                rs += p;
            }
        rs += __shfl_xor(rs, 16);
        rs += __shfl_xor(rs, 32);
        l_i = l_i * al + rs;
        unsigned int p0[8], p1[8];
        #pragma unroll
        for (int j = 0; j < 8; j++) {
            pk4 pf;
            pf.h = bf16x4{(bf16)sacc[j][0], (bf16)sacc[j][1],
                          (bf16)sacc[j][2], (bf16)sacc[j][3]};
            p0[j] = pf.d[0]; p1[j] = pf.d[1];
        }
        const int srcA = lr + 16 * ((2 * quad) & 3);
        const int srcB = lr + 16 * ((2 * quad + 1) & 3);
        const bool hi = (quad >> 1) != 0;
        #pragma unroll
        for (int c = 0; c < 4; c++) {
            unsigned int a0 = __shfl(p0[2*c], srcA), a1 = __shfl(p0[2*c+1], srcA);
            unsigned int b0 = __shfl(p1[2*c], srcA), b1 = __shfl(p1[2*c+1], srcA);
            unsigned int c0 = __shfl(p0[2*c], srcB), c1 = __shfl(p0[2*c+1], srcB);
            unsigned int d0 = __shfl(p1[2*c], srcB), d1 = __shfl(p1[2*c+1], srcB);
            unsigned int fr[4];
            fr[0] = hi ? a1 : a0;
            fr[1] = hi ? b1 : b0;
            fr[2] = hi ? c1 : c0;
            fr[3] = hi ? d1 : d0;
            bf16x8 pf8 = *(bf16x8*)fr;
            #pragma unroll
            for (int fb = 0; fb < 4; fb++) {
                bf16x8 vf8 = *(const bf16x8*)&Vs[fb*16 + lr][c*32 + quad*8];
                o_accT[fb] = MFMA32(vf8, pf8, o_accT[fb]);
            }
        }
#endif
    }

    // epilogue: divide, transpose through reused Ks LDS, coalesced stores
    __syncthreads();                      // all waves done reading Ks/Vs
    bf16 (*OsE)[68] = (bf16(*)[68])&Ks[0][0];    // 64 x 68 bf16 = 8.7KB
    const float inv = 1.0f / l_i;
    const int sil = wave * 16 + lr;       // local si 0..63
    #pragma unroll
    for (int fb = 0; fb < 4; fb++)
        #pragma unroll
        for (int r = 0; r < 4; r++)
            OsE[sil][fb*16 + quad*4 + r] = (bf16)(o_accT[fb][r] * inv);
    __syncthreads();
    const int row = t >> 2, seg = (t & 3) * 16;
    bf16* dst = o_ws + ((size_t)b_ * 2048 + qt*64 + row) * 1024 + h*64 + seg;
    *(bf16x8*)(dst)     = *(const bf16x8*)&OsE[row][seg];
    *(bf16x8*)(dst + 8) = *(const bf16x8*)&OsE[row][seg + 8];
}

// ---------------------------------------------------------------------------
// Kernel 3: output projection.  64x128 tiles, grid (64,8), BK=64 + swizzle.
// ---------------------------------------------------------------------------
__global__ __launch_bounds__(256, 3)
void out_gemm(const bf16* __restrict__ o_ws,
              const bf16* __restrict__ wob, const float* __restrict__ bo,
              float* __restrict__ out)
{
    __shared__ bf16 As[64][64];
    __shared__ bf16 Bs[128][64];
    __shared__ float Ot[64][68];   // 17.4KB epilogue staging

    const int m0 = blockIdx.x * 64;
    const int n0 = blockIdx.y * 128;
    const int t    = threadIdx.x;
    const int wave = t >> 6;
    const int lane = t & 63;
    const int lr   = lane & 15;
    const int quad = lane >> 4;
    const int wm = (wave & 1) * 32;
    const int wn = (wave >> 1) * 64;

    const int srow8 = lane >> 3;
    const int pcol  = (lane & 7) * 8;
    const int gcol  = ((lane & 7) ^ (lane >> 3)) * 8;
    // A: 64 rows -> 2 instr/wave; B: 128 rows -> 4 instr/wave
    const bf16* gaU[2]; bf16* laU[2];
    #pragma unroll
    for (int u = 0; u < 2; u++) {
        const int row = wave * 16 + u * 8 + srow8;
        gaU[u] = o_ws + (size_t)(m0 + row) * 1024 + gcol;
        laU[u] = &As[row][pcol];
    }
    const bf16* gbU[4]; bf16* lbU[4];
    #pragma unroll
    for (int u = 0; u < 4; u++) {
        const int row = wave * 32 + u * 8 + srow8;
        gbU[u] = wob + (size_t)(n0 + row) * 1024 + gcol;
        lbU[u] = &Bs[row][pcol];
    }
    const int swA = (lr & 7) * 8;

    f32x4 acc[2][4] = {};

    for (int k0 = 0; k0 < 1024; k0 += 64) {
        #pragma unroll
        for (int u = 0; u < 2; u++) GLL(gaU[u] + k0, laU[u]);
        #pragma unroll
        for (int u = 0; u < 4; u++) GLL(gbU[u] + k0, lbU[u]);
        __syncthreads();

        bf16x8 af[2][2], bfr[4][2];
        #pragma unroll
        for (int i = 0; i < 2; i++)
            #pragma unroll
            for (int kc = 0; kc < 2; kc++)
                af[i][kc] = *(const bf16x8*)&As[wm + i*16 + lr][(kc*32 + quad*8) ^ swA];
        #pragma unroll
        for (int j = 0; j < 4; j++)
            #pragma unroll
            for (int kc = 0; kc < 2; kc++)
                bfr[j][kc] = *(const bf16x8*)&Bs[wn + j*16 + lr][(kc*32 + quad*8) ^ swA];
        #pragma unroll
        for (int kc = 0; kc < 2; kc++)
            #pragma unroll
            for (int i = 0; i < 2; i++)
                #pragma unroll
                for (int j = 0; j < 4; j++)
                    acc[i][j] = MFMA32(af[i][kc], bfr[j][kc], acc[i][j]);
        __syncthreads();
    }

    #pragma unroll
    for (int ph = 0; ph < 2; ph++) {
        if ((wave >> 1) == ph) {
            #pragma unroll
            for (int j = 0; j < 4; j++) {
                const float bb = bo[n0 + ph * 64 + j * 16 + lr];
                #pragma unroll
                for (int i = 0; i < 2; i++)
                    #pragma unroll
                    for (int r = 0; r < 4; r++)
                        Ot[wm + i*16 + quad*4 + r][j*16 + lr] = acc[i][j][r] + bb;
            }
        }
        __syncthreads();
        const int row = t >> 2, seg = (t & 3) * 16;
        float* dst = out + (size_t)(m0 + row) * 1024 + n0 + ph * 64 + seg;
        #pragma unroll
        for (int e = 0; e < 4; e++)
            *(float4*)(dst + e * 4) = *(const float4*)&Ot[row][seg + e * 4];
        __syncthreads();
    }
}

extern "C" void kernel_launch(void* const* d_in, const int* in_sizes, int n_in,
                              void* d_out, int out_size, void* d_ws, size_t ws_size,
                              hipStream_t stream) {
    (void)in_sizes; (void)n_in; (void)out_size; (void)ws_size;
    const float* x  = (const float*)d_in[0];
    const float* Wq = (const float*)d_in[1];
    const float* bq = (const float*)d_in[2];
    const float* Wk = (const float*)d_in[3];
    const float* bk = (const float*)d_in[4];
    const float* Wv = (const float*)d_in[5];
    const float* bv = (const float*)d_in[6];
    const float* Wo = (const float*)d_in[7];
    const float* bo = (const float*)d_in[8];
    float* out = (float*)d_out;

    char* ws = (char*)d_ws;
    const size_t MB = 1024 * 1024;
    bf16* xb   = (bf16*)(ws);
    bf16* wqb  = (bf16*)(ws + 8 * MB);
    bf16* wkb  = (bf16*)(ws + 10 * MB);
    bf16* wvb  = (bf16*)(ws + 12 * MB);
    bf16* wob  = (bf16*)(ws + 14 * MB);
    bf16* q_ws = (bf16*)(ws + 16 * MB);
    bf16* k_ws = (bf16*)(ws + 24 * MB);
    bf16* v_ws = (bf16*)(ws + 32 * MB);
    bf16* o_ws = (bf16*)(ws + 40 * MB);

    hipLaunchKernelGGL(cvt_bf16, dim3(8192), dim3(256), 0, stream,
                       x, Wq, Wk, Wv, Wo, xb, wqb, wkb, wvb, wob);
    hipLaunchKernelGGL(qkv_gemm, dim3(32, 8, 3), dim3(256), 0, stream,
                       xb, wqb, bq, wkb, bk, wvb, bv, q_ws, k_ws, v_ws);
    hipLaunchKernelGGL(attn, dim3(32, 32), dim3(256), 0, stream,
                       q_ws, k_ws, v_ws, o_ws);
    hipLaunchKernelGGL(out_gemm, dim3(64, 8), dim3(256), 0, stream,
                       o_ws, wob, bo, out);
}